// Round 4
// baseline (7665.536 us; speedup 1.0000x reference)
//
#include <hip/hip_runtime.h>
#include <math.h>
#include <type_traits>

// Fused MLP head with BINARY output gated by a per-row rank-k comparison.
// Hypothesis (r3): harness's np reference is float64 end-to-end; any fp32
// rounding anywhere flips ~1-3 of 16384 rows => absmax 1.0. So: fp64
// storage + accumulation everywhere. Correctness probe, not speed.
//
// ws-size-proof: B and H chunked host-side (arithmetic only, capture-safe).
//   ws layout per chunk: L[Bc][F] fp64 logits | h64[Bc][Hc] fp64 hidden.

#define BM 128
#define BN 128
#define BK 16

// out64 = epilogue(A @ W^T), A:(M,K) TA ld=lda, W:(N,*) fp32 ld=ldw.
// MODE 0: relu(acc+bias)  -> out64   (GEMM1 -> h64 chunk)
// MODE 1: acc+bias        -> out64   (GEMM2, first H-chunk)
// MODE 2: out64 += acc              (GEMM2, later H-chunks)
template<typename TA, int MODE>
__global__ __launch_bounds__(256, 1) void gemm64(
    const TA* __restrict__ A, int lda,
    const float* __restrict__ W, int ldw,
    const float* __restrict__ bias,
    double* __restrict__ out64, int N, int K)
{
    __shared__ double As[BK][BM + 2];
    __shared__ double Bs[BK][BN + 2];
    const int t  = threadIdx.x;
    const int tm = t >> 4;          // 0..15
    const int tn = t & 15;          // 0..15
    const size_t bm = blockIdx.x;
    const size_t bn = blockIdx.y;
    const TA*    Ab = A + bm * BM * (size_t)lda;
    const float* Wb = W + bn * BN * (size_t)ldw;

    double acc[8][8] = {};

    for (int k0 = 0; k0 < K; k0 += BK) {
        #pragma unroll
        for (int i = 0; i < 2; ++i) {
            int f   = t + i * 256;       // 0..511
            int row = f >> 2;            // 0..127
            int kc  = (f & 3) << 2;      // 0,4,8,12
            if constexpr (std::is_same<TA, double>::value) {
                double2 v0 = *(const double2*)(Ab + (size_t)row * lda + k0 + kc);
                double2 v1 = *(const double2*)(Ab + (size_t)row * lda + k0 + kc + 2);
                As[kc + 0][row] = v0.x; As[kc + 1][row] = v0.y;
                As[kc + 2][row] = v1.x; As[kc + 3][row] = v1.y;
            } else {
                float4 va = *(const float4*)(Ab + (size_t)row * lda + k0 + kc);
                As[kc + 0][row] = (double)va.x; As[kc + 1][row] = (double)va.y;
                As[kc + 2][row] = (double)va.z; As[kc + 3][row] = (double)va.w;
            }
            float4 vb = *(const float4*)(Wb + (size_t)row * ldw + k0 + kc);
            Bs[kc + 0][row] = (double)vb.x; Bs[kc + 1][row] = (double)vb.y;
            Bs[kc + 2][row] = (double)vb.z; Bs[kc + 3][row] = (double)vb.w;
        }
        __syncthreads();
        #pragma unroll
        for (int k = 0; k < BK; ++k) {
            double a[8], b[8];
            #pragma unroll
            for (int i = 0; i < 4; ++i) {
                *(double2*)&a[i * 2] = *(const double2*)&As[k][tm * 8 + i * 2];
                *(double2*)&b[i * 2] = *(const double2*)&Bs[k][tn * 8 + i * 2];
            }
            #pragma unroll
            for (int i = 0; i < 8; ++i)
                #pragma unroll
                for (int j = 0; j < 8; ++j)
                    acc[i][j] = fma(a[i], b[j], acc[i][j]);
        }
        __syncthreads();
    }

    double bv[8];
    if (MODE != 2) {
        #pragma unroll
        for (int j = 0; j < 8; ++j) bv[j] = (double)bias[bn * BN + tn * 8 + j];
    }

    #pragma unroll
    for (int i = 0; i < 8; ++i) {
        size_t row  = bm * BM + (size_t)tm * 8 + i;
        size_t base = row * (size_t)N + bn * BN + tn * 8;
        #pragma unroll
        for (int j = 0; j < 8; ++j) {
            double v = acc[i][j];
            if (MODE == 0) out64[base + j] = fmax(v + bv[j], 0.0);
            if (MODE == 1) out64[base + j] = v + bv[j];
            if (MODE == 2) out64[base + j] += v;
        }
    }
}

// One wave per row of ncols(=512) fp64 logits: sigmoid in fp64, iterative
// top-k extraction with (value,index) tie-break (top_k multiset semantics),
// gate (s >= kth && s > 0.2) in fp64, write fp32 0/1.
__global__ __launch_bounds__(256) void topk64_kernel(
    const double* __restrict__ L, float* __restrict__ O, int ncols,
    const int* __restrict__ kp)
{
    const int wave = threadIdx.x >> 6;
    const int lane = threadIdx.x & 63;
    const int k = *kp;
    const size_t row = (size_t)blockIdx.x * 4 + wave;
    const double* Lr = L + row * (size_t)ncols;

    double v[8];
    #pragma unroll
    for (int j = 0; j < 8; ++j) {
        double l = Lr[lane * 8 + j];
        v[j] = 1.0 / (1.0 + exp(-l));
    }
    double w[8];
    #pragma unroll
    for (int j = 0; j < 8; ++j) w[j] = v[j];

    double kth = -1.0e300;
    for (int it = 0; it < k; ++it) {
        double mv = w[0]; int mj = 0;
        #pragma unroll
        for (int j = 1; j < 8; ++j)
            if (w[j] > mv) { mv = w[j]; mj = j; }
        int mi = lane * 8 + mj;
        #pragma unroll
        for (int off = 32; off; off >>= 1) {
            double ov = __shfl_xor(mv, off);
            int    oi = __shfl_xor(mi, off);
            if (ov > mv || (ov == mv && oi < mi)) { mv = ov; mi = oi; }
        }
        kth = mv;
        if ((mi >> 3) == lane) w[mi & 7] = -1.0e300;
    }

    float o[8];
    #pragma unroll
    for (int j = 0; j < 8; ++j)
        o[j] = (v[j] >= kth && v[j] > 0.2) ? 1.0f : 0.0f;
    float* Op = O + row * (size_t)ncols + lane * 8;
    *(float4*)&Op[0] = *(const float4*)&o[0];
    *(float4*)&Op[4] = *(const float4*)&o[4];
}

extern "C" void kernel_launch(void* const* d_in, const int* in_sizes, int n_in,
                              void* d_out, int out_size, void* d_ws, size_t ws_size,
                              hipStream_t stream) {
    const float* inp = (const float*)d_in[0];
    const float* W1  = (const float*)d_in[1];
    const float* b1  = (const float*)d_in[2];
    const float* W2  = (const float*)d_in[3];
    const float* b2  = (const float*)d_in[4];
    const int*   kp  = (const int*)d_in[5];

    const int H = in_sizes[2];              // 2048
    const int F = in_sizes[4];              // 512
    const int D = in_sizes[1] / H;          // 4096
    const int B = in_sizes[0] / D;          // 16384
    float* out = (float*)d_out;

    // Chunk sizing (host arithmetic only): L[Bc][F] + h64[Bc][Hc], fp64.
    int Hc = H;
    int Bc = 0;
    for (;;) {
        size_t perRow = (size_t)F * 8 + (size_t)Hc * 8;
        Bc = (int)((ws_size / perRow) / BM) * BM;
        if (Bc >= BM || Hc <= BM) break;
        Hc >>= 1;
    }
    if (Bc < BM) Bc = BM;
    if (Bc > B)  Bc = B;

    double* L   = (double*)d_ws;                 // Bc x F
    double* h64 = L + (size_t)Bc * F;            // Bc x Hc

    for (int b0 = 0; b0 < B; b0 += Bc) {
        int bc = (B - b0 < Bc) ? (B - b0) : Bc;
        for (int h0 = 0; h0 < H; h0 += Hc) {
            int hc = (H - h0 < Hc) ? (H - h0) : Hc;
            // GEMM1 chunk: h64[bc][hc] = relu64(inp[b0..] @ W1[h0..]^T + b1[h0..])
            gemm64<float, 0><<<dim3(bc / BM, hc / BN), 256, 0, stream>>>(
                inp + (size_t)b0 * D, D, W1 + (size_t)h0 * D, D, b1 + h0,
                h64, hc, D);
            // GEMM2 chunk: L[bc][F] (init|+=) h64 @ W2[:, h0..]^T (+ b2)
            if (h0 == 0)
                gemm64<double, 1><<<dim3(bc / BM, F / BN), 256, 0, stream>>>(
                    h64, hc, W2 + h0, H, b2, L, F, hc);
            else
                gemm64<double, 2><<<dim3(bc / BM, F / BN), 256, 0, stream>>>(
                    h64, hc, W2 + h0, H, b2, L, F, hc);
        }
        topk64_kernel<<<bc / 4, 256, 0, stream>>>(L, out + (size_t)b0 * F, F, kp);
    }
}

// Round 5
// 6939.437 us; speedup vs baseline: 1.1046x; 1.1046x over previous
//
#include <hip/hip_runtime.h>
#include <math.h>
#include <type_traits>

// Fused MLP head with BINARY output (per-row top-k gate + 0.2 hardlim).
// r3 verified: harness ref is fp64 end-to-end; fp64 pipeline passed absmax 0.
// r4 strategy: fp32 fast pass for all rows, margin analysis in logit space,
// fp64 recompute (the r3-verified kernels, gathered) for only the ~3% of rows
// whose rank-8/9 gap or 0.2-proximity is below a provable worst-case fp32
// noise bound (3e-4 < tau=1e-3). Repair kernels: fixed grid + early exit on
// device counter (graph-capture safe). Gating in logit space is exact under
// sigmoid monotonicity; near-ties are flagged and resolved in fp64 s-space.

#define BM 128
#define BN 128
#define BK 16

#define TAU      1.0e-3f
#define L02F    -1.3862943611198906f   /* ln(0.2/0.8) */

// ---------------- fp32 GEMM (type-translated from verified gemm64) --------
// MODE 0: C = relu(acc+bias)   MODE 1: C = acc+bias (logits)
template<int MODE>
__global__ __launch_bounds__(256) void sgemm32(
    const float* __restrict__ A, int lda,
    const float* __restrict__ W, int ldw,
    const float* __restrict__ bias,
    float* __restrict__ C, int N, int K)
{
    __shared__ float As[BK][BM + 2];
    __shared__ float Bs[BK][BN + 2];
    const int t  = threadIdx.x;
    const int tm = t >> 4;
    const int tn = t & 15;
    const size_t bm = blockIdx.x;
    const size_t bn = blockIdx.y;
    const float* Ab = A + bm * BM * (size_t)lda;
    const float* Wb = W + bn * BN * (size_t)ldw;

    float acc[8][8] = {};

    for (int k0 = 0; k0 < K; k0 += BK) {
        #pragma unroll
        for (int i = 0; i < 2; ++i) {
            int f   = t + i * 256;
            int row = f >> 2;
            int kc  = (f & 3) << 2;
            float4 va = *(const float4*)(Ab + (size_t)row * lda + k0 + kc);
            As[kc + 0][row] = va.x; As[kc + 1][row] = va.y;
            As[kc + 2][row] = va.z; As[kc + 3][row] = va.w;
            float4 vb = *(const float4*)(Wb + (size_t)row * ldw + k0 + kc);
            Bs[kc + 0][row] = vb.x; Bs[kc + 1][row] = vb.y;
            Bs[kc + 2][row] = vb.z; Bs[kc + 3][row] = vb.w;
        }
        __syncthreads();
        #pragma unroll
        for (int k = 0; k < BK; ++k) {
            float a[8], b[8];
            *(float4*)&a[0] = *(const float4*)&As[k][tm * 8];
            *(float4*)&a[4] = *(const float4*)&As[k][tm * 8 + 4];
            *(float4*)&b[0] = *(const float4*)&Bs[k][tn * 8];
            *(float4*)&b[4] = *(const float4*)&Bs[k][tn * 8 + 4];
            #pragma unroll
            for (int i = 0; i < 8; ++i)
                #pragma unroll
                for (int j = 0; j < 8; ++j)
                    acc[i][j] = fmaf(a[i], b[j], acc[i][j]);
        }
        __syncthreads();
    }

    float bv[8];
    #pragma unroll
    for (int j = 0; j < 8; ++j) bv[j] = bias[bn * BN + tn * 8 + j];

    #pragma unroll
    for (int i = 0; i < 8; ++i) {
        size_t row  = bm * BM + (size_t)tm * 8 + i;
        size_t base = row * (size_t)N + bn * BN + tn * 8;
        float o[8];
        #pragma unroll
        for (int j = 0; j < 8; ++j) {
            float v = acc[i][j] + bv[j];
            o[j] = (MODE == 0) ? fmaxf(v, 0.0f) : v;
        }
        *(float4*)&C[base]     = *(const float4*)&o[0];
        *(float4*)&C[base + 4] = *(const float4*)&o[4];
    }
}

// ---------------- fp64 GEMM (verified r3; + optional early-exit) -----------
// MODE 0: relu(acc+bias) -> out64   MODE 1: acc+bias -> out64   MODE 2: +=
template<typename TA, int MODE>
__global__ __launch_bounds__(256, 1) void gemm64(
    const TA* __restrict__ A, int lda,
    const float* __restrict__ W, int ldw,
    const float* __restrict__ bias,
    double* __restrict__ out64, int N, int K,
    const int* __restrict__ cnt, int maxr)
{
    if (cnt) {
        int c = *cnt; if (c > maxr) c = maxr;
        if ((int)blockIdx.x * BM >= c) return;
    }
    __shared__ double As[BK][BM + 2];
    __shared__ double Bs[BK][BN + 2];
    const int t  = threadIdx.x;
    const int tm = t >> 4;
    const int tn = t & 15;
    const size_t bm = blockIdx.x;
    const size_t bn = blockIdx.y;
    const TA*    Ab = A + bm * BM * (size_t)lda;
    const float* Wb = W + bn * BN * (size_t)ldw;

    double acc[8][8] = {};

    for (int k0 = 0; k0 < K; k0 += BK) {
        #pragma unroll
        for (int i = 0; i < 2; ++i) {
            int f   = t + i * 256;
            int row = f >> 2;
            int kc  = (f & 3) << 2;
            if constexpr (std::is_same<TA, double>::value) {
                double2 v0 = *(const double2*)(Ab + (size_t)row * lda + k0 + kc);
                double2 v1 = *(const double2*)(Ab + (size_t)row * lda + k0 + kc + 2);
                As[kc + 0][row] = v0.x; As[kc + 1][row] = v0.y;
                As[kc + 2][row] = v1.x; As[kc + 3][row] = v1.y;
            } else {
                float4 va = *(const float4*)(Ab + (size_t)row * lda + k0 + kc);
                As[kc + 0][row] = (double)va.x; As[kc + 1][row] = (double)va.y;
                As[kc + 2][row] = (double)va.z; As[kc + 3][row] = (double)va.w;
            }
            float4 vb = *(const float4*)(Wb + (size_t)row * ldw + k0 + kc);
            Bs[kc + 0][row] = (double)vb.x; Bs[kc + 1][row] = (double)vb.y;
            Bs[kc + 2][row] = (double)vb.z; Bs[kc + 3][row] = (double)vb.w;
        }
        __syncthreads();
        #pragma unroll
        for (int k = 0; k < BK; ++k) {
            double a[8], b[8];
            #pragma unroll
            for (int i = 0; i < 4; ++i) {
                *(double2*)&a[i * 2] = *(const double2*)&As[k][tm * 8 + i * 2];
                *(double2*)&b[i * 2] = *(const double2*)&Bs[k][tn * 8 + i * 2];
            }
            #pragma unroll
            for (int i = 0; i < 8; ++i)
                #pragma unroll
                for (int j = 0; j < 8; ++j)
                    acc[i][j] = fma(a[i], b[j], acc[i][j]);
        }
        __syncthreads();
    }

    double bv[8];
    if (MODE != 2) {
        #pragma unroll
        for (int j = 0; j < 8; ++j) bv[j] = (double)bias[bn * BN + tn * 8 + j];
    }

    #pragma unroll
    for (int i = 0; i < 8; ++i) {
        size_t row  = bm * BM + (size_t)tm * 8 + i;
        size_t base = row * (size_t)N + bn * BN + tn * 8;
        #pragma unroll
        for (int j = 0; j < 8; ++j) {
            double v = acc[i][j];
            if (MODE == 0) out64[base + j] = fmax(v + bv[j], 0.0);
            if (MODE == 1) out64[base + j] = v + bv[j];
            if (MODE == 2) out64[base + j] += v;
        }
    }
}

// ---------------- fp64 GEMM1 with row gather (repair path) -----------------
__global__ __launch_bounds__(256, 1) void repair_gemm1(
    const float* __restrict__ inp, int D,
    const float* __restrict__ W1, const float* __restrict__ b1,
    double* __restrict__ h64, int H,
    const int* __restrict__ risky, const int* __restrict__ cnt, int maxr)
{
    {
        int c = *cnt; if (c > maxr) c = maxr;
        if ((int)blockIdx.x * BM >= c) return;
    }
    __shared__ double As[BK][BM + 2];
    __shared__ double Bs[BK][BN + 2];
    const int t  = threadIdx.x;
    const int tm = t >> 4;
    const int tn = t & 15;
    const size_t bm = blockIdx.x;
    const size_t bn = blockIdx.y;
    const int r0 = t >> 2;            // staging row, i=0
    const int r1 = r0 + 64;           // staging row, i=1
    const float* Arow0 = inp + (size_t)risky[bm * BM + r0] * D;
    const float* Arow1 = inp + (size_t)risky[bm * BM + r1] * D;
    const float* Wb = W1 + bn * BN * (size_t)D;

    double acc[8][8] = {};

    for (int k0 = 0; k0 < D; k0 += BK) {
        #pragma unroll
        for (int i = 0; i < 2; ++i) {
            int row = i ? r1 : r0;
            int kc  = (t & 3) << 2;
            const float* Ap = (i ? Arow1 : Arow0) + k0 + kc;
            float4 va = *(const float4*)Ap;
            As[kc + 0][row] = (double)va.x; As[kc + 1][row] = (double)va.y;
            As[kc + 2][row] = (double)va.z; As[kc + 3][row] = (double)va.w;
            float4 vb = *(const float4*)(Wb + (size_t)row * D + k0 + kc);
            Bs[kc + 0][row] = (double)vb.x; Bs[kc + 1][row] = (double)vb.y;
            Bs[kc + 2][row] = (double)vb.z; Bs[kc + 3][row] = (double)vb.w;
        }
        __syncthreads();
        #pragma unroll
        for (int k = 0; k < BK; ++k) {
            double a[8], b[8];
            #pragma unroll
            for (int i = 0; i < 4; ++i) {
                *(double2*)&a[i * 2] = *(const double2*)&As[k][tm * 8 + i * 2];
                *(double2*)&b[i * 2] = *(const double2*)&Bs[k][tn * 8 + i * 2];
            }
            #pragma unroll
            for (int i = 0; i < 8; ++i)
                #pragma unroll
                for (int j = 0; j < 8; ++j)
                    acc[i][j] = fma(a[i], b[j], acc[i][j]);
        }
        __syncthreads();
    }

    double bv[8];
    #pragma unroll
    for (int j = 0; j < 8; ++j) bv[j] = (double)b1[bn * BN + tn * 8 + j];

    #pragma unroll
    for (int i = 0; i < 8; ++i) {
        size_t row  = bm * BM + (size_t)tm * 8 + i;   // compact slot
        size_t base = row * (size_t)H + bn * BN + tn * 8;
        #pragma unroll
        for (int j = 0; j < 8; ++j)
            h64[base + j] = fmax(acc[i][j] + bv[j], 0.0);
    }
}

// ---------------- init: zero risky list + counter ---------------------------
__global__ void init_repair(int* risky, int* cnt, int maxr)
{
    int i = blockIdx.x * 256 + threadIdx.x;
    if (i == 0) *cnt = 0;
    if (i < maxr) risky[i] = 0;
}

// ---------------- fp32 top-k + margin flag + gate (logit space) ------------
__global__ __launch_bounds__(256) void margin_topk32(
    const float* __restrict__ L, float* __restrict__ O, int ncols,
    const int* __restrict__ kp, int* __restrict__ risky, int* __restrict__ cnt,
    int maxr)
{
    const int wave = threadIdx.x >> 6;
    const int lane = threadIdx.x & 63;
    const int k = *kp;
    const size_t row = (size_t)blockIdx.x * 4 + wave;
    const float* Lr = L + row * (size_t)ncols;

    float v[8];
    *(float4*)&v[0] = *(const float4*)(Lr + lane * 8);
    *(float4*)&v[4] = *(const float4*)(Lr + lane * 8 + 4);
    float w[8];
    #pragma unroll
    for (int j = 0; j < 8; ++j) w[j] = v[j];

    float kth = -3.0e38f, minD = 3.0e38f;
    for (int it = 0; it < k; ++it) {
        float mv = w[0]; int mj = 0;
        #pragma unroll
        for (int j = 1; j < 8; ++j)
            if (w[j] > mv) { mv = w[j]; mj = j; }
        int mi = lane * 8 + mj;
        #pragma unroll
        for (int off = 32; off; off >>= 1) {
            float ov = __shfl_xor(mv, off);
            int   oi = __shfl_xor(mi, off);
            if (ov > mv || (ov == mv && oi < mi)) { mv = ov; mi = oi; }
        }
        kth = mv;
        minD = fminf(minD, fabsf(mv - L02F));
        if ((mi >> 3) == lane) w[mi & 7] = -3.0e38f;
    }
    // next-best (rank k+1) for the gap
    float nv = w[0];
    #pragma unroll
    for (int j = 1; j < 8; ++j) nv = fmaxf(nv, w[j]);
    #pragma unroll
    for (int off = 32; off; off >>= 1) nv = fmaxf(nv, __shfl_xor(nv, off));

    bool risk = ((kth - nv) < 2.0f * TAU) || (minD < TAU);
    if (risk && lane == 0) {
        int p = atomicAdd(cnt, 1);
        if (p < maxr) risky[p] = (int)row;
    }

    float o[8];
    #pragma unroll
    for (int j = 0; j < 8; ++j)
        o[j] = (v[j] >= kth && v[j] > L02F) ? 1.0f : 0.0f;
    float* Op = O + row * (size_t)ncols + lane * 8;
    *(float4*)&Op[0] = *(const float4*)&o[0];
    *(float4*)&Op[4] = *(const float4*)&o[4];
}

// ---------------- fp64 top-k (verified r3), direct or gathered -------------
__global__ __launch_bounds__(256) void topk64_kernel(
    const double* __restrict__ L, float* __restrict__ O, int ncols,
    const int* __restrict__ kp,
    const int* __restrict__ risky, const int* __restrict__ cnt, int maxr)
{
    const int wave = threadIdx.x >> 6;
    const int lane = threadIdx.x & 63;
    const int k = *kp;
    size_t pos = (size_t)blockIdx.x * 4 + wave;
    size_t row = pos;
    if (cnt) {
        int c = *cnt; if (c > maxr) c = maxr;
        if ((int)pos >= c) return;
        row = (size_t)risky[pos];
    }
    const double* Lr = L + pos * (size_t)ncols;

    double v[8];
    #pragma unroll
    for (int j = 0; j < 8; ++j) {
        double l = Lr[lane * 8 + j];
        v[j] = 1.0 / (1.0 + exp(-l));
    }
    double w[8];
    #pragma unroll
    for (int j = 0; j < 8; ++j) w[j] = v[j];

    double kth = -1.0e300;
    for (int it = 0; it < k; ++it) {
        double mv = w[0]; int mj = 0;
        #pragma unroll
        for (int j = 1; j < 8; ++j)
            if (w[j] > mv) { mv = w[j]; mj = j; }
        int mi = lane * 8 + mj;
        #pragma unroll
        for (int off = 32; off; off >>= 1) {
            double ov = __shfl_xor(mv, off);
            int    oi = __shfl_xor(mi, off);
            if (ov > mv || (ov == mv && oi < mi)) { mv = ov; mi = oi; }
        }
        kth = mv;
        if ((mi >> 3) == lane) w[mi & 7] = -1.0e300;
    }

    float o[8];
    #pragma unroll
    for (int j = 0; j < 8; ++j)
        o[j] = (v[j] >= kth && v[j] > 0.2) ? 1.0f : 0.0f;
    float* Op = O + row * (size_t)ncols + lane * 8;
    *(float4*)&Op[0] = *(const float4*)&o[0];
    *(float4*)&Op[4] = *(const float4*)&o[4];
}

extern "C" void kernel_launch(void* const* d_in, const int* in_sizes, int n_in,
                              void* d_out, int out_size, void* d_ws, size_t ws_size,
                              hipStream_t stream) {
    const float* inp = (const float*)d_in[0];
    const float* W1  = (const float*)d_in[1];
    const float* b1  = (const float*)d_in[2];
    const float* W2  = (const float*)d_in[3];
    const float* b2  = (const float*)d_in[4];
    const int*   kp  = (const int*)d_in[5];

    const int H = in_sizes[2];              // 2048
    const int F = in_sizes[4];              // 512
    const int D = in_sizes[1] / H;          // 4096
    const int B = in_sizes[0] / D;          // 16384
    float* out = (float*)d_out;

    const int MAXR = B / 2;                 // 8192; aliasing sizes exact
    const size_t szH32 = (size_t)B * H * 4; // 128 MiB
    const size_t szL32 = (size_t)B * F * 4; //  32 MiB
    const size_t needMain = szH32 + szL32 + (size_t)MAXR * 4 + 256;

    if (ws_size >= needMain) {
        float*  h32   = (float*)d_ws;
        float*  l32   = (float*)((char*)d_ws + szH32);
        int*    risky = (int*)((char*)d_ws + szH32 + szL32);
        int*    cnt   = risky + MAXR;
        double* h64   = (double*)d_ws;                    // alias h32 (consumed)
        double* L64   = (double*)((char*)d_ws + szH32);   // alias l32 (consumed)

        init_repair<<<(MAXR + 255) / 256, 256, 0, stream>>>(risky, cnt, MAXR);
        sgemm32<0><<<dim3(B / BM, H / BN), 256, 0, stream>>>(
            inp, D, W1, D, b1, h32, H, D);
        sgemm32<1><<<dim3(B / BM, F / BN), 256, 0, stream>>>(
            h32, H, W2, H, b2, l32, F, H);
        margin_topk32<<<B / 4, 256, 0, stream>>>(l32, out, F, kp, risky, cnt, MAXR);
        repair_gemm1<<<dim3(MAXR / BM, H / BN), 256, 0, stream>>>(
            inp, D, W1, b1, h64, H, risky, cnt, MAXR);
        gemm64<double, 1><<<dim3(MAXR / BM, F / BN), 256, 0, stream>>>(
            h64, H, W2, H, b2, L64, F, H, cnt, MAXR);
        topk64_kernel<<<MAXR / 4, 256, 0, stream>>>(L64, out, F, kp, risky, cnt, MAXR);
    } else {
        // Fallback: full-fp64 chunked pipeline (verified r3).
        int Hc = H, Bc = 0;
        for (;;) {
            size_t perRow = (size_t)F * 8 + (size_t)Hc * 8;
            Bc = (int)((ws_size / perRow) / BM) * BM;
            if (Bc >= BM || Hc <= BM) break;
            Hc >>= 1;
        }
        if (Bc < BM) Bc = BM;
        if (Bc > B)  Bc = B;
        double* L   = (double*)d_ws;
        double* h64 = L + (size_t)Bc * F;

        for (int b0 = 0; b0 < B; b0 += Bc) {
            int bc = (B - b0 < Bc) ? (B - b0) : Bc;
            for (int h0 = 0; h0 < H; h0 += Hc) {
                int hc = (H - h0 < Hc) ? (H - h0) : Hc;
                gemm64<float, 0><<<dim3(bc / BM, hc / BN), 256, 0, stream>>>(
                    inp + (size_t)b0 * D, D, W1 + (size_t)h0 * D, D, b1 + h0,
                    h64, hc, D, nullptr, 0);
                if (h0 == 0)
                    gemm64<double, 1><<<dim3(bc / BM, F / BN), 256, 0, stream>>>(
                        h64, hc, W2 + h0, H, b2, L, F, hc, nullptr, 0);
                else
                    gemm64<double, 2><<<dim3(bc / BM, F / BN), 256, 0, stream>>>(
                        h64, hc, W2 + h0, H, b2, L, F, hc, nullptr, 0);
            }
            topk64_kernel<<<bc / 4, 256, 0, stream>>>(
                L, out + (size_t)b0 * F, F, kp, nullptr, nullptr, 0);
        }
    }
}

// Round 6
// 3546.783 us; speedup vs baseline: 2.1613x; 1.9565x over previous
//
#include <hip/hip_runtime.h>
#include <math.h>
#include <type_traits>

// Fused MLP head with BINARY output (per-row top-k gate + 0.2 hardlim).
// Architecture (r4-verified): fast pass all rows -> margin flags -> fp64
// repair of flagged rows only. r5: fast pass moves from fp32 VALU (61 TF)
// to bf16-split MFMA (hi+lo truncation split, 4 cross products, fp32 acc).
// Split residual <= |x|*2^-16 per element -> logit noise RMS ~1e-5, vs
// flag margin TAU=1e-3 (~100 sigma) -> flips impossible outside the
// flagged set, which the r3-verified fp64 pipeline recomputes exactly.
//
// ws layout byte-identical to r4's proven footprint:
//   [0, 2^27)        h_hi | h_lo  (bf16 B x H each)   -- aliased by h64 repair
//   [2^27, +32MiB)   l32 fp32 logits                  -- aliased by L64 repair
//   then risky[MAXR] + cnt

#define BM 128
#define BN 128
#define BK 16      // fp64 path K-step
#define BKF 32     // bf16 path K-step

#define TAU   1.0e-3f
#define L02F -1.3862943611198906f   /* ln(0.2/0.8) */

typedef __attribute__((ext_vector_type(8))) short bf16x8;
typedef __attribute__((ext_vector_type(4))) float f32x4;

// Truncation bf16 helpers (1-2 int ops each; residual one-sided < ulp).
__device__ inline ushort bfhi(float f)   { return (ushort)(__float_as_uint(f) >> 16); }
__device__ inline float  bfhif(float f)  { return __uint_as_float(__float_as_uint(f) & 0xFFFF0000u); }

// ---------------- bf16-split MFMA GEMM (fast pass) -------------------------
// Computes C = epilogue(A @ W^T + bias) with A,W split into hi/lo bf16.
// A_PRESPLIT 0: A fp32 (convert in staging). 1: A pre-split (Ahg, Alg).
// OUT_MODE   0: relu -> split-store (Chi, Clo). 1: fp32 logits -> C32.
template<int A_PRESPLIT, int OUT_MODE>
__global__ __launch_bounds__(256) void bgemm_split(
    const float*  __restrict__ A32,
    const ushort* __restrict__ Ahg, const ushort* __restrict__ Alg, int lda,
    const float*  __restrict__ W,   int ldw,
    const float*  __restrict__ bias,
    ushort* __restrict__ Chi, ushort* __restrict__ Clo,
    float*  __restrict__ C32, int N, int K)
{
    __shared__ __align__(16) ushort Ah[BM * BKF];
    __shared__ __align__(16) ushort Al[BM * BKF];
    __shared__ __align__(16) ushort Bh[BN * BKF];
    __shared__ __align__(16) ushort Bl[BN * BKF];

    const int t    = threadIdx.x;
    const int lane = t & 63;
    const int wave = t >> 6;
    const int wr   = wave >> 1;          // 0..1 : 64-row block
    const int wc   = wave & 1;           // 0..1 : 64-col block
    const int l15  = lane & 15;
    const int l4   = lane >> 4;          // 0..3
    const size_t bm = blockIdx.x;
    const size_t bn = blockIdx.y;

    f32x4 acc[4][4];
    #pragma unroll
    for (int mi = 0; mi < 4; ++mi)
        #pragma unroll
        for (int ni = 0; ni < 4; ++ni)
            acc[mi][ni] = (f32x4){0.f, 0.f, 0.f, 0.f};

    for (int k0 = 0; k0 < K; k0 += BKF) {
        // ---- stage A tile [128 rows][32 k] as hi/lo bf16
        if (A_PRESPLIT) {
            #pragma unroll
            for (int i = 0; i < 2; ++i) {
                int c = t + i * 256;                 // 0..511
                int row = c >> 2, q = c & 3;
                size_t g = (bm * BM + row) * (size_t)lda + k0 + q * 8;
                *(uint4*)&Ah[row * BKF + q * 8] = *(const uint4*)(Ahg + g);
                *(uint4*)&Al[row * BKF + q * 8] = *(const uint4*)(Alg + g);
            }
        } else {
            #pragma unroll
            for (int i = 0; i < 4; ++i) {
                int c = t + i * 256;                 // 0..1023
                int row = c >> 3, q = c & 7;
                float4 v = *(const float4*)(A32 + (bm * BM + row) * (size_t)lda + k0 + q * 4);
                ushort4 h, l;
                h.x = bfhi(v.x); l.x = bfhi(v.x - bfhif(v.x));
                h.y = bfhi(v.y); l.y = bfhi(v.y - bfhif(v.y));
                h.z = bfhi(v.z); l.z = bfhi(v.z - bfhif(v.z));
                h.w = bfhi(v.w); l.w = bfhi(v.w - bfhif(v.w));
                *(ushort4*)&Ah[row * BKF + q * 4] = h;
                *(ushort4*)&Al[row * BKF + q * 4] = l;
            }
        }
        // ---- stage W tile [128 n][32 k] as hi/lo bf16 (always fp32 source)
        #pragma unroll
        for (int i = 0; i < 4; ++i) {
            int c = t + i * 256;
            int row = c >> 3, q = c & 7;
            float4 v = *(const float4*)(W + (bn * BN + row) * (size_t)ldw + k0 + q * 4);
            ushort4 h, l;
            h.x = bfhi(v.x); l.x = bfhi(v.x - bfhif(v.x));
            h.y = bfhi(v.y); l.y = bfhi(v.y - bfhif(v.y));
            h.z = bfhi(v.z); l.z = bfhi(v.z - bfhif(v.z));
            h.w = bfhi(v.w); l.w = bfhi(v.w - bfhif(v.w));
            *(ushort4*)&Bh[row * BKF + q * 4] = h;
            *(ushort4*)&Bl[row * BKF + q * 4] = l;
        }
        __syncthreads();

        // ---- fragments: m/n = lane&15, k-octet = lane>>4 (any consistent
        // k-permutation is exact since A and B share the instruction's k-wiring)
        bf16x8 ah[4], al[4], bh[4], bl[4];
        #pragma unroll
        for (int mi = 0; mi < 4; ++mi) {
            int r = wr * 64 + mi * 16 + l15;
            ah[mi] = *(const bf16x8*)&Ah[r * BKF + l4 * 8];
            al[mi] = *(const bf16x8*)&Al[r * BKF + l4 * 8];
        }
        #pragma unroll
        for (int ni = 0; ni < 4; ++ni) {
            int r = wc * 64 + ni * 16 + l15;
            bh[ni] = *(const bf16x8*)&Bh[r * BKF + l4 * 8];
            bl[ni] = *(const bf16x8*)&Bl[r * BKF + l4 * 8];
        }
        #pragma unroll
        for (int mi = 0; mi < 4; ++mi)
            #pragma unroll
            for (int ni = 0; ni < 4; ++ni) {
                acc[mi][ni] = __builtin_amdgcn_mfma_f32_16x16x32_bf16(ah[mi], bh[ni], acc[mi][ni], 0, 0, 0);
                acc[mi][ni] = __builtin_amdgcn_mfma_f32_16x16x32_bf16(ah[mi], bl[ni], acc[mi][ni], 0, 0, 0);
                acc[mi][ni] = __builtin_amdgcn_mfma_f32_16x16x32_bf16(al[mi], bh[ni], acc[mi][ni], 0, 0, 0);
                acc[mi][ni] = __builtin_amdgcn_mfma_f32_16x16x32_bf16(al[mi], bl[ni], acc[mi][ni], 0, 0, 0);
            }
        __syncthreads();
    }

    // ---- epilogue. C/D layout (m89-verified): col=lane&15, row=4*(lane>>4)+r
    #pragma unroll
    for (int ni = 0; ni < 4; ++ni) {
        int col = (int)bn * BN + wc * 64 + ni * 16 + l15;
        float bv = bias[col];
        #pragma unroll
        for (int mi = 0; mi < 4; ++mi) {
            int rowb = (int)bm * BM + wr * 64 + mi * 16 + l4 * 4;
            #pragma unroll
            for (int r = 0; r < 4; ++r) {
                float v = acc[mi][ni][r] + bv;
                size_t idx = (size_t)(rowb + r) * N + col;
                if (OUT_MODE == 0) {
                    v = fmaxf(v, 0.0f);
                    Chi[idx] = bfhi(v);
                    Clo[idx] = bfhi(v - bfhif(v));
                } else {
                    C32[idx] = v;
                }
            }
        }
    }
}

// ---------------- fp64 GEMM (verified r3/r4; repair + fallback) ------------
template<typename TA, int MODE>
__global__ __launch_bounds__(256, 1) void gemm64(
    const TA* __restrict__ A, int lda,
    const float* __restrict__ W, int ldw,
    const float* __restrict__ bias,
    double* __restrict__ out64, int N, int K,
    const int* __restrict__ cnt, int maxr)
{
    if (cnt) {
        int c = *cnt; if (c > maxr) c = maxr;
        if ((int)blockIdx.x * BM >= c) return;
    }
    __shared__ double As[BK][BM + 2];
    __shared__ double Bs[BK][BN + 2];
    const int t  = threadIdx.x;
    const int tm = t >> 4;
    const int tn = t & 15;
    const size_t bm = blockIdx.x;
    const size_t bn = blockIdx.y;
    const TA*    Ab = A + bm * BM * (size_t)lda;
    const float* Wb = W + bn * BN * (size_t)ldw;

    double acc[8][8] = {};

    for (int k0 = 0; k0 < K; k0 += BK) {
        #pragma unroll
        for (int i = 0; i < 2; ++i) {
            int f   = t + i * 256;
            int row = f >> 2;
            int kc  = (f & 3) << 2;
            if constexpr (std::is_same<TA, double>::value) {
                double2 v0 = *(const double2*)(Ab + (size_t)row * lda + k0 + kc);
                double2 v1 = *(const double2*)(Ab + (size_t)row * lda + k0 + kc + 2);
                As[kc + 0][row] = v0.x; As[kc + 1][row] = v0.y;
                As[kc + 2][row] = v1.x; As[kc + 3][row] = v1.y;
            } else {
                float4 va = *(const float4*)(Ab + (size_t)row * lda + k0 + kc);
                As[kc + 0][row] = (double)va.x; As[kc + 1][row] = (double)va.y;
                As[kc + 2][row] = (double)va.z; As[kc + 3][row] = (double)va.w;
            }
            float4 vb = *(const float4*)(Wb + (size_t)row * ldw + k0 + kc);
            Bs[kc + 0][row] = (double)vb.x; Bs[kc + 1][row] = (double)vb.y;
            Bs[kc + 2][row] = (double)vb.z; Bs[kc + 3][row] = (double)vb.w;
        }
        __syncthreads();
        #pragma unroll
        for (int k = 0; k < BK; ++k) {
            double a[8], b[8];
            #pragma unroll
            for (int i = 0; i < 4; ++i) {
                *(double2*)&a[i * 2] = *(const double2*)&As[k][tm * 8 + i * 2];
                *(double2*)&b[i * 2] = *(const double2*)&Bs[k][tn * 8 + i * 2];
            }
            #pragma unroll
            for (int i = 0; i < 8; ++i)
                #pragma unroll
                for (int j = 0; j < 8; ++j)
                    acc[i][j] = fma(a[i], b[j], acc[i][j]);
        }
        __syncthreads();
    }

    double bv[8];
    if (MODE != 2) {
        #pragma unroll
        for (int j = 0; j < 8; ++j) bv[j] = (double)bias[bn * BN + tn * 8 + j];
    }

    #pragma unroll
    for (int i = 0; i < 8; ++i) {
        size_t row  = bm * BM + (size_t)tm * 8 + i;
        size_t base = row * (size_t)N + bn * BN + tn * 8;
        #pragma unroll
        for (int j = 0; j < 8; ++j) {
            double v = acc[i][j];
            if (MODE == 0) out64[base + j] = fmax(v + bv[j], 0.0);
            if (MODE == 1) out64[base + j] = v + bv[j];
            if (MODE == 2) out64[base + j] += v;
        }
    }
}

// ---------------- fp64 GEMM1 with row gather (repair, verified r4) ---------
__global__ __launch_bounds__(256, 1) void repair_gemm1(
    const float* __restrict__ inp, int D,
    const float* __restrict__ W1, const float* __restrict__ b1,
    double* __restrict__ h64, int H,
    const int* __restrict__ risky, const int* __restrict__ cnt, int maxr)
{
    {
        int c = *cnt; if (c > maxr) c = maxr;
        if ((int)blockIdx.x * BM >= c) return;
    }
    __shared__ double As[BK][BM + 2];
    __shared__ double Bs[BK][BN + 2];
    const int t  = threadIdx.x;
    const int tm = t >> 4;
    const int tn = t & 15;
    const size_t bm = blockIdx.x;
    const size_t bn = blockIdx.y;
    const int r0 = t >> 2;
    const int r1 = r0 + 64;
    const float* Arow0 = inp + (size_t)risky[bm * BM + r0] * D;
    const float* Arow1 = inp + (size_t)risky[bm * BM + r1] * D;
    const float* Wb = W1 + bn * BN * (size_t)D;

    double acc[8][8] = {};

    for (int k0 = 0; k0 < D; k0 += BK) {
        #pragma unroll
        for (int i = 0; i < 2; ++i) {
            int row = i ? r1 : r0;
            int kc  = (t & 3) << 2;
            const float* Ap = (i ? Arow1 : Arow0) + k0 + kc;
            float4 va = *(const float4*)Ap;
            As[kc + 0][row] = (double)va.x; As[kc + 1][row] = (double)va.y;
            As[kc + 2][row] = (double)va.z; As[kc + 3][row] = (double)va.w;
            float4 vb = *(const float4*)(Wb + (size_t)row * D + k0 + kc);
            Bs[kc + 0][row] = (double)vb.x; Bs[kc + 1][row] = (double)vb.y;
            Bs[kc + 2][row] = (double)vb.z; Bs[kc + 3][row] = (double)vb.w;
        }
        __syncthreads();
        #pragma unroll
        for (int k = 0; k < BK; ++k) {
            double a[8], b[8];
            #pragma unroll
            for (int i = 0; i < 4; ++i) {
                *(double2*)&a[i * 2] = *(const double2*)&As[k][tm * 8 + i * 2];
                *(double2*)&b[i * 2] = *(const double2*)&Bs[k][tn * 8 + i * 2];
            }
            #pragma unroll
            for (int i = 0; i < 8; ++i)
                #pragma unroll
                for (int j = 0; j < 8; ++j)
                    acc[i][j] = fma(a[i], b[j], acc[i][j]);
        }
        __syncthreads();
    }

    double bv[8];
    #pragma unroll
    for (int j = 0; j < 8; ++j) bv[j] = (double)b1[bn * BN + tn * 8 + j];

    #pragma unroll
    for (int i = 0; i < 8; ++i) {
        size_t row  = bm * BM + (size_t)tm * 8 + i;
        size_t base = row * (size_t)H + bn * BN + tn * 8;
        #pragma unroll
        for (int j = 0; j < 8; ++j)
            h64[base + j] = fmax(acc[i][j] + bv[j], 0.0);
    }
}

__global__ void init_repair(int* risky, int* cnt, int maxr)
{
    int i = blockIdx.x * 256 + threadIdx.x;
    if (i == 0) *cnt = 0;
    if (i < maxr) risky[i] = 0;
}

// ---------------- fp32 top-k + margin flag + gate (verified r4) ------------
__global__ __launch_bounds__(256) void margin_topk32(
    const float* __restrict__ L, float* __restrict__ O, int ncols,
    const int* __restrict__ kp, int* __restrict__ risky, int* __restrict__ cnt,
    int maxr)
{
    const int wave = threadIdx.x >> 6;
    const int lane = threadIdx.x & 63;
    const int k = *kp;
    const size_t row = (size_t)blockIdx.x * 4 + wave;
    const float* Lr = L + row * (size_t)ncols;

    float v[8];
    *(float4*)&v[0] = *(const float4*)(Lr + lane * 8);
    *(float4*)&v[4] = *(const float4*)(Lr + lane * 8 + 4);
    float w[8];
    #pragma unroll
    for (int j = 0; j < 8; ++j) w[j] = v[j];

    float kth = -3.0e38f, minD = 3.0e38f;
    for (int it = 0; it < k; ++it) {
        float mv = w[0]; int mj = 0;
        #pragma unroll
        for (int j = 1; j < 8; ++j)
            if (w[j] > mv) { mv = w[j]; mj = j; }
        int mi = lane * 8 + mj;
        #pragma unroll
        for (int off = 32; off; off >>= 1) {
            float ov = __shfl_xor(mv, off);
            int   oi = __shfl_xor(mi, off);
            if (ov > mv || (ov == mv && oi < mi)) { mv = ov; mi = oi; }
        }
        kth = mv;
        minD = fminf(minD, fabsf(mv - L02F));
        if ((mi >> 3) == lane) w[mi & 7] = -3.0e38f;
    }
    float nv = w[0];
    #pragma unroll
    for (int j = 1; j < 8; ++j) nv = fmaxf(nv, w[j]);
    #pragma unroll
    for (int off = 32; off; off >>= 1) nv = fmaxf(nv, __shfl_xor(nv, off));

    bool risk = ((kth - nv) < 2.0f * TAU) || (minD < TAU);
    if (risk && lane == 0) {
        int p = atomicAdd(cnt, 1);
        if (p < maxr) risky[p] = (int)row;
    }

    float o[8];
    #pragma unroll
    for (int j = 0; j < 8; ++j)
        o[j] = (v[j] >= kth && v[j] > L02F) ? 1.0f : 0.0f;
    float* Op = O + row * (size_t)ncols + lane * 8;
    *(float4*)&Op[0] = *(const float4*)&o[0];
    *(float4*)&Op[4] = *(const float4*)&o[4];
}

// ---------------- fp64 top-k (verified r3), direct or gathered -------------
__global__ __launch_bounds__(256) void topk64_kernel(
    const double* __restrict__ L, float* __restrict__ O, int ncols,
    const int* __restrict__ kp,
    const int* __restrict__ risky, const int* __restrict__ cnt, int maxr)
{
    const int wave = threadIdx.x >> 6;
    const int lane = threadIdx.x & 63;
    const int k = *kp;
    size_t pos = (size_t)blockIdx.x * 4 + wave;
    size_t row = pos;
    if (cnt) {
        int c = *cnt; if (c > maxr) c = maxr;
        if ((int)pos >= c) return;
        row = (size_t)risky[pos];
    }
    const double* Lr = L + pos * (size_t)ncols;

    double v[8];
    #pragma unroll
    for (int j = 0; j < 8; ++j) {
        double l = Lr[lane * 8 + j];
        v[j] = 1.0 / (1.0 + exp(-l));
    }
    double w[8];
    #pragma unroll
    for (int j = 0; j < 8; ++j) w[j] = v[j];

    double kth = -1.0e300;
    for (int it = 0; it < k; ++it) {
        double mv = w[0]; int mj = 0;
        #pragma unroll
        for (int j = 1; j < 8; ++j)
            if (w[j] > mv) { mv = w[j]; mj = j; }
        int mi = lane * 8 + mj;
        #pragma unroll
        for (int off = 32; off; off >>= 1) {
            double ov = __shfl_xor(mv, off);
            int    oi = __shfl_xor(mi, off);
            if (ov > mv || (ov == mv && oi < mi)) { mv = ov; mi = oi; }
        }
        kth = mv;
        if ((mi >> 3) == lane) w[mi & 7] = -1.0e300;
    }

    float o[8];
    #pragma unroll
    for (int j = 0; j < 8; ++j)
        o[j] = (v[j] >= kth && v[j] > 0.2) ? 1.0f : 0.0f;
    float* Op = O + row * (size_t)ncols + lane * 8;
    *(float4*)&Op[0] = *(const float4*)&o[0];
    *(float4*)&Op[4] = *(const float4*)&o[4];
}

extern "C" void kernel_launch(void* const* d_in, const int* in_sizes, int n_in,
                              void* d_out, int out_size, void* d_ws, size_t ws_size,
                              hipStream_t stream) {
    const float* inp = (const float*)d_in[0];
    const float* W1  = (const float*)d_in[1];
    const float* b1  = (const float*)d_in[2];
    const float* W2  = (const float*)d_in[3];
    const float* b2  = (const float*)d_in[4];
    const int*   kp  = (const int*)d_in[5];

    const int H = in_sizes[2];              // 2048
    const int F = in_sizes[4];              // 512
    const int D = in_sizes[1] / H;          // 4096
    const int B = in_sizes[0] / D;          // 16384
    float* out = (float*)d_out;

    const int MAXR = B / 2;                          // 8192
    const size_t szHsplit = (size_t)B * H * 2 * 2;   // h_hi + h_lo = 2^27 B
    const size_t szL32    = (size_t)B * F * 4;       // 32 MiB
    const size_t needMain = szHsplit + szL32 + (size_t)MAXR * 4 + 256;

    if (ws_size >= needMain) {
        ushort* h_hi  = (ushort*)d_ws;
        ushort* h_lo  = h_hi + (size_t)B * H;
        float*  l32   = (float*)((char*)d_ws + szHsplit);
        int*    risky = (int*)((char*)d_ws + szHsplit + szL32);
        int*    cnt   = risky + MAXR;
        double* h64   = (double*)d_ws;                      // alias h_hi/h_lo
        double* L64   = (double*)((char*)d_ws + szHsplit);  // alias l32

        init_repair<<<(MAXR + 255) / 256, 256, 0, stream>>>(risky, cnt, MAXR);
        // fast pass: bf16-split MFMA
        bgemm_split<0, 0><<<dim3(B / BM, H / BN), 256, 0, stream>>>(
            inp, nullptr, nullptr, D, W1, D, b1, h_hi, h_lo, nullptr, H, D);
        bgemm_split<1, 1><<<dim3(B / BM, F / BN), 256, 0, stream>>>(
            nullptr, h_hi, h_lo, H, W2, H, b2, nullptr, nullptr, l32, F, H);
        margin_topk32<<<B / 4, 256, 0, stream>>>(l32, out, F, kp, risky, cnt, MAXR);
        // repair flagged rows in fp64 (r3-verified numerics)
        repair_gemm1<<<dim3(MAXR / BM, H / BN), 256, 0, stream>>>(
            inp, D, W1, b1, h64, H, risky, cnt, MAXR);
        gemm64<double, 1><<<dim3(MAXR / BM, F / BN), 256, 0, stream>>>(
            h64, H, W2, H, b2, L64, F, H, cnt, MAXR);
        topk64_kernel<<<MAXR / 4, 256, 0, stream>>>(L64, out, F, kp, risky, cnt, MAXR);
    } else {
        // Fallback: full-fp64 chunked pipeline (verified r3).
        int Hc = H, Bc = 0;
        for (;;) {
            size_t perRow = (size_t)F * 8 + (size_t)Hc * 8;
            Bc = (int)((ws_size / perRow) / BM) * BM;
            if (Bc >= BM || Hc <= BM) break;
            Hc >>= 1;
        }
        if (Bc < BM) Bc = BM;
        if (Bc > B)  Bc = B;
        double* L   = (double*)d_ws;
        double* h64 = L + (size_t)Bc * F;

        for (int b0 = 0; b0 < B; b0 += Bc) {
            int bc = (B - b0 < Bc) ? (B - b0) : Bc;
            for (int h0 = 0; h0 < H; h0 += Hc) {
                int hc = (H - h0 < Hc) ? (H - h0) : Hc;
                gemm64<float, 0><<<dim3(bc / BM, hc / BN), 256, 0, stream>>>(
                    inp + (size_t)b0 * D, D, W1 + (size_t)h0 * D, D, b1 + h0,
                    h64, hc, D, nullptr, 0);
                if (h0 == 0)
                    gemm64<double, 1><<<dim3(bc / BM, F / BN), 256, 0, stream>>>(
                        h64, hc, W2 + h0, H, b2, L, F, hc, nullptr, 0);
                else
                    gemm64<double, 2><<<dim3(bc / BM, F / BN), 256, 0, stream>>>(
                        h64, hc, W2 + h0, H, b2, L, F, hc, nullptr, 0);
            }
            topk64_kernel<<<bc / 4, 256, 0, stream>>>(
                L, out + (size_t)b0 * F, F, kp, nullptr, nullptr, 0);
        }
    }
}

// Round 7
// 3094.978 us; speedup vs baseline: 2.4768x; 1.1460x over previous
//
#include <hip/hip_runtime.h>
#include <math.h>
#include <type_traits>

// Fused MLP head with BINARY output (per-row top-k gate + 0.2 hardlim).
// Verified architecture: bf16-split MFMA fast pass (r5) -> logit-margin flags
// -> fp64 recompute of flagged rows only (r3-verified numerics).
// r6: repair kernels re-tiled 128-row -> 16-row (parallelism-starved before:
// 2.04 ms at 12% VALUBusy), TAU 1e-3 -> 1e-4 (split-error bias is relative,
// random part RMS ~4e-6 -> 1e-4 is >=20 sigma; flag count ~10x lower).

#define BM 128
#define BN 128
#define BK 16      // fp64 path K-step
#define BKF 32     // bf16 path K-step

#define TAU   1.0e-4f
#define L02F -1.3862943611198906f   /* ln(0.2/0.8) */

typedef __attribute__((ext_vector_type(8))) short bf16x8;
typedef __attribute__((ext_vector_type(4))) float f32x4;

__device__ inline ushort bfhi(float f)   { return (ushort)(__float_as_uint(f) >> 16); }
__device__ inline float  bfhif(float f)  { return __uint_as_float(__float_as_uint(f) & 0xFFFF0000u); }

// ---------------- bf16-split MFMA GEMM (fast pass, r5-verified) ------------
template<int A_PRESPLIT, int OUT_MODE>
__global__ __launch_bounds__(256) void bgemm_split(
    const float*  __restrict__ A32,
    const ushort* __restrict__ Ahg, const ushort* __restrict__ Alg, int lda,
    const float*  __restrict__ W,   int ldw,
    const float*  __restrict__ bias,
    ushort* __restrict__ Chi, ushort* __restrict__ Clo,
    float*  __restrict__ C32, int N, int K)
{
    __shared__ __align__(16) ushort Ah[BM * BKF];
    __shared__ __align__(16) ushort Al[BM * BKF];
    __shared__ __align__(16) ushort Bh[BN * BKF];
    __shared__ __align__(16) ushort Bl[BN * BKF];

    const int t    = threadIdx.x;
    const int lane = t & 63;
    const int wave = t >> 6;
    const int wr   = wave >> 1;
    const int wc   = wave & 1;
    const int l15  = lane & 15;
    const int l4   = lane >> 4;
    const size_t bm = blockIdx.x;
    const size_t bn = blockIdx.y;

    f32x4 acc[4][4];
    #pragma unroll
    for (int mi = 0; mi < 4; ++mi)
        #pragma unroll
        for (int ni = 0; ni < 4; ++ni)
            acc[mi][ni] = (f32x4){0.f, 0.f, 0.f, 0.f};

    for (int k0 = 0; k0 < K; k0 += BKF) {
        if (A_PRESPLIT) {
            #pragma unroll
            for (int i = 0; i < 2; ++i) {
                int c = t + i * 256;
                int row = c >> 2, q = c & 3;
                size_t g = (bm * BM + row) * (size_t)lda + k0 + q * 8;
                *(uint4*)&Ah[row * BKF + q * 8] = *(const uint4*)(Ahg + g);
                *(uint4*)&Al[row * BKF + q * 8] = *(const uint4*)(Alg + g);
            }
        } else {
            #pragma unroll
            for (int i = 0; i < 4; ++i) {
                int c = t + i * 256;
                int row = c >> 3, q = c & 7;
                float4 v = *(const float4*)(A32 + (bm * BM + row) * (size_t)lda + k0 + q * 4);
                ushort4 h, l;
                h.x = bfhi(v.x); l.x = bfhi(v.x - bfhif(v.x));
                h.y = bfhi(v.y); l.y = bfhi(v.y - bfhif(v.y));
                h.z = bfhi(v.z); l.z = bfhi(v.z - bfhif(v.z));
                h.w = bfhi(v.w); l.w = bfhi(v.w - bfhif(v.w));
                *(ushort4*)&Ah[row * BKF + q * 4] = h;
                *(ushort4*)&Al[row * BKF + q * 4] = l;
            }
        }
        #pragma unroll
        for (int i = 0; i < 4; ++i) {
            int c = t + i * 256;
            int row = c >> 3, q = c & 7;
            float4 v = *(const float4*)(W + (bn * BN + row) * (size_t)ldw + k0 + q * 4);
            ushort4 h, l;
            h.x = bfhi(v.x); l.x = bfhi(v.x - bfhif(v.x));
            h.y = bfhi(v.y); l.y = bfhi(v.y - bfhif(v.y));
            h.z = bfhi(v.z); l.z = bfhi(v.z - bfhif(v.z));
            h.w = bfhi(v.w); l.w = bfhi(v.w - bfhif(v.w));
            *(ushort4*)&Bh[row * BKF + q * 4] = h;
            *(ushort4*)&Bl[row * BKF + q * 4] = l;
        }
        __syncthreads();

        bf16x8 ah[4], al[4], bh[4], bl[4];
        #pragma unroll
        for (int mi = 0; mi < 4; ++mi) {
            int r = wr * 64 + mi * 16 + l15;
            ah[mi] = *(const bf16x8*)&Ah[r * BKF + l4 * 8];
            al[mi] = *(const bf16x8*)&Al[r * BKF + l4 * 8];
        }
        #pragma unroll
        for (int ni = 0; ni < 4; ++ni) {
            int r = wc * 64 + ni * 16 + l15;
            bh[ni] = *(const bf16x8*)&Bh[r * BKF + l4 * 8];
            bl[ni] = *(const bf16x8*)&Bl[r * BKF + l4 * 8];
        }
        #pragma unroll
        for (int mi = 0; mi < 4; ++mi)
            #pragma unroll
            for (int ni = 0; ni < 4; ++ni) {
                acc[mi][ni] = __builtin_amdgcn_mfma_f32_16x16x32_bf16(ah[mi], bh[ni], acc[mi][ni], 0, 0, 0);
                acc[mi][ni] = __builtin_amdgcn_mfma_f32_16x16x32_bf16(ah[mi], bl[ni], acc[mi][ni], 0, 0, 0);
                acc[mi][ni] = __builtin_amdgcn_mfma_f32_16x16x32_bf16(al[mi], bh[ni], acc[mi][ni], 0, 0, 0);
                acc[mi][ni] = __builtin_amdgcn_mfma_f32_16x16x32_bf16(al[mi], bl[ni], acc[mi][ni], 0, 0, 0);
            }
        __syncthreads();
    }

    #pragma unroll
    for (int ni = 0; ni < 4; ++ni) {
        int col = (int)bn * BN + wc * 64 + ni * 16 + l15;
        float bv = bias[col];
        #pragma unroll
        for (int mi = 0; mi < 4; ++mi) {
            int rowb = (int)bm * BM + wr * 64 + mi * 16 + l4 * 4;
            #pragma unroll
            for (int r = 0; r < 4; ++r) {
                float v = acc[mi][ni][r] + bv;
                size_t idx = (size_t)(rowb + r) * N + col;
                if (OUT_MODE == 0) {
                    v = fmaxf(v, 0.0f);
                    Chi[idx] = bfhi(v);
                    Clo[idx] = bfhi(v - bfhif(v));
                } else {
                    C32[idx] = v;
                }
            }
        }
    }
}

// ---------------- 16-row fp64 repair GEMM ----------------------------------
// MODE 0: gathered rows (risky idx), TA=float, relu(acc+bias) -> out64 compact
// MODE 1: compact rows,              TA=double, acc+bias      -> out64 compact
// Block: 16 rows x 128 cols; thread (rw = t>>4, cg = t&15) owns 1 row x 8 cols.
// W tile in LDS grouped 8-doubles-stride-10 (read conflicts 8-way -> ~2-way).
template<typename TA, int MODE>
__global__ __launch_bounds__(256) void repair16(
    const TA* __restrict__ A, int lda,
    const float* __restrict__ W, int ldw,
    const float* __restrict__ bias,
    double* __restrict__ out64, int N, int K,
    const int* __restrict__ risky, const int* __restrict__ cnt, int maxr)
{
    {
        int c = *cnt; if (c > maxr) c = maxr;
        if ((int)blockIdx.x * 16 >= c) return;
    }
    __shared__ double As[BK][16 + 2];
    __shared__ double Bs[BK][160];      // 16 groups x (8 data + 2 pad)
    const int t  = threadIdx.x;
    const int rw = t >> 4;              // 0..15 row in tile
    const int cg = t & 15;              // 0..15 col group
    const size_t bm = blockIdx.x;
    const size_t bn = blockIdx.y;

    const TA* Arow;
    if (MODE == 0) Arow = A + (size_t)risky[bm * 16 + rw] * lda;
    else           Arow = A + (bm * 16 + rw) * (size_t)lda;
    const float* Wb = W + bn * BN * (size_t)ldw;

    double acc[8] = {};

    for (int k0 = 0; k0 < K; k0 += BK) {
        // stage A: 16 rows x 16 k; thread loads exactly one element.
        As[cg][rw] = (double)Arow[k0 + cg];
        // stage W: 128 cols x 16 k (gemm64 pattern, grouped-pad layout)
        #pragma unroll
        for (int i = 0; i < 2; ++i) {
            int f   = t + i * 256;
            int row = f >> 2;
            int kc  = (f & 3) << 2;
            int gp  = (row >> 3) * 10 + (row & 7);
            float4 vb = *(const float4*)(Wb + (size_t)row * ldw + k0 + kc);
            Bs[kc + 0][gp] = (double)vb.x; Bs[kc + 1][gp] = (double)vb.y;
            Bs[kc + 2][gp] = (double)vb.z; Bs[kc + 3][gp] = (double)vb.w;
        }
        __syncthreads();
        #pragma unroll
        for (int k = 0; k < BK; ++k) {
            double a = As[k][rw];
            double b[8];
            const double* bp = &Bs[k][cg * 10];
            #pragma unroll
            for (int i = 0; i < 4; ++i)
                *(double2*)&b[i * 2] = *(const double2*)&bp[i * 2];
            #pragma unroll
            for (int j = 0; j < 8; ++j)
                acc[j] = fma(a, b[j], acc[j]);
        }
        __syncthreads();
    }

    size_t slot = bm * 16 + rw;
    size_t base = slot * (size_t)N + bn * BN + cg * 8;
    #pragma unroll
    for (int j = 0; j < 8; ++j) {
        double v = acc[j] + (double)bias[bn * BN + cg * 8 + j];
        out64[base + j] = (MODE == 0) ? fmax(v, 0.0) : v;
    }
}

// ---------------- fp64 GEMM (r3-verified; fallback tier only) --------------
template<typename TA, int MODE>
__global__ __launch_bounds__(256, 1) void gemm64(
    const TA* __restrict__ A, int lda,
    const float* __restrict__ W, int ldw,
    const float* __restrict__ bias,
    double* __restrict__ out64, int N, int K)
{
    __shared__ double As[BK][BM + 2];
    __shared__ double Bs[BK][BN + 2];
    const int t  = threadIdx.x;
    const int tm = t >> 4;
    const int tn = t & 15;
    const size_t bm = blockIdx.x;
    const size_t bn = blockIdx.y;
    const TA*    Ab = A + bm * BM * (size_t)lda;
    const float* Wb = W + bn * BN * (size_t)ldw;

    double acc[8][8] = {};

    for (int k0 = 0; k0 < K; k0 += BK) {
        #pragma unroll
        for (int i = 0; i < 2; ++i) {
            int f   = t + i * 256;
            int row = f >> 2;
            int kc  = (f & 3) << 2;
            if constexpr (std::is_same<TA, double>::value) {
                double2 v0 = *(const double2*)(Ab + (size_t)row * lda + k0 + kc);
                double2 v1 = *(const double2*)(Ab + (size_t)row * lda + k0 + kc + 2);
                As[kc + 0][row] = v0.x; As[kc + 1][row] = v0.y;
                As[kc + 2][row] = v1.x; As[kc + 3][row] = v1.y;
            } else {
                float4 va = *(const float4*)(Ab + (size_t)row * lda + k0 + kc);
                As[kc + 0][row] = (double)va.x; As[kc + 1][row] = (double)va.y;
                As[kc + 2][row] = (double)va.z; As[kc + 3][row] = (double)va.w;
            }
            float4 vb = *(const float4*)(Wb + (size_t)row * ldw + k0 + kc);
            Bs[kc + 0][row] = (double)vb.x; Bs[kc + 1][row] = (double)vb.y;
            Bs[kc + 2][row] = (double)vb.z; Bs[kc + 3][row] = (double)vb.w;
        }
        __syncthreads();
        #pragma unroll
        for (int k = 0; k < BK; ++k) {
            double a[8], b[8];
            #pragma unroll
            for (int i = 0; i < 4; ++i) {
                *(double2*)&a[i * 2] = *(const double2*)&As[k][tm * 8 + i * 2];
                *(double2*)&b[i * 2] = *(const double2*)&Bs[k][tn * 8 + i * 2];
            }
            #pragma unroll
            for (int i = 0; i < 8; ++i)
                #pragma unroll
                for (int j = 0; j < 8; ++j)
                    acc[i][j] = fma(a[i], b[j], acc[i][j]);
        }
        __syncthreads();
    }

    double bv[8];
    if (MODE != 2) {
        #pragma unroll
        for (int j = 0; j < 8; ++j) bv[j] = (double)bias[bn * BN + tn * 8 + j];
    }

    #pragma unroll
    for (int i = 0; i < 8; ++i) {
        size_t row  = bm * BM + (size_t)tm * 8 + i;
        size_t base = row * (size_t)N + bn * BN + tn * 8;
        #pragma unroll
        for (int j = 0; j < 8; ++j) {
            double v = acc[i][j];
            if (MODE == 0) out64[base + j] = fmax(v + bv[j], 0.0);
            if (MODE == 1) out64[base + j] = v + bv[j];
            if (MODE == 2) out64[base + j] += v;
        }
    }
}

__global__ void init_repair(int* risky, int* cnt, int maxr)
{
    int i = blockIdx.x * 256 + threadIdx.x;
    if (i == 0) *cnt = 0;
    if (i < maxr) risky[i] = 0;
}

// ---------------- fp32 top-k + margin flag + gate (r4-verified) ------------
__global__ __launch_bounds__(256) void margin_topk32(
    const float* __restrict__ L, float* __restrict__ O, int ncols,
    const int* __restrict__ kp, int* __restrict__ risky, int* __restrict__ cnt,
    int maxr)
{
    const int wave = threadIdx.x >> 6;
    const int lane = threadIdx.x & 63;
    const int k = *kp;
    const size_t row = (size_t)blockIdx.x * 4 + wave;
    const float* Lr = L + row * (size_t)ncols;

    float v[8];
    *(float4*)&v[0] = *(const float4*)(Lr + lane * 8);
    *(float4*)&v[4] = *(const float4*)(Lr + lane * 8 + 4);
    float w[8];
    #pragma unroll
    for (int j = 0; j < 8; ++j) w[j] = v[j];

    float kth = -3.0e38f, minD = 3.0e38f;
    for (int it = 0; it < k; ++it) {
        float mv = w[0]; int mj = 0;
        #pragma unroll
        for (int j = 1; j < 8; ++j)
            if (w[j] > mv) { mv = w[j]; mj = j; }
        int mi = lane * 8 + mj;
        #pragma unroll
        for (int off = 32; off; off >>= 1) {
            float ov = __shfl_xor(mv, off);
            int   oi = __shfl_xor(mi, off);
            if (ov > mv || (ov == mv && oi < mi)) { mv = ov; mi = oi; }
        }
        kth = mv;
        minD = fminf(minD, fabsf(mv - L02F));
        if ((mi >> 3) == lane) w[mi & 7] = -3.0e38f;
    }
    float nv = w[0];
    #pragma unroll
    for (int j = 1; j < 8; ++j) nv = fmaxf(nv, w[j]);
    #pragma unroll
    for (int off = 32; off; off >>= 1) nv = fmaxf(nv, __shfl_xor(nv, off));

    bool risk = ((kth - nv) < 2.0f * TAU) || (minD < TAU);
    if (risk && lane == 0) {
        int p = atomicAdd(cnt, 1);
        if (p < maxr) risky[p] = (int)row;
    }

    float o[8];
    #pragma unroll
    for (int j = 0; j < 8; ++j)
        o[j] = (v[j] >= kth && v[j] > L02F) ? 1.0f : 0.0f;
    float* Op = O + row * (size_t)ncols + lane * 8;
    *(float4*)&Op[0] = *(const float4*)&o[0];
    *(float4*)&Op[4] = *(const float4*)&o[4];
}

// ---------------- fp64 top-k (r3-verified), direct or gathered -------------
__global__ __launch_bounds__(256) void topk64_kernel(
    const double* __restrict__ L, float* __restrict__ O, int ncols,
    const int* __restrict__ kp,
    const int* __restrict__ risky, const int* __restrict__ cnt, int maxr)
{
    const int wave = threadIdx.x >> 6;
    const int lane = threadIdx.x & 63;
    const int k = *kp;
    size_t pos = (size_t)blockIdx.x * 4 + wave;
    size_t row = pos;
    if (cnt) {
        int c = *cnt; if (c > maxr) c = maxr;
        if ((int)pos >= c) return;
        row = (size_t)risky[pos];
    }
    const double* Lr = L + pos * (size_t)ncols;

    double v[8];
    #pragma unroll
    for (int j = 0; j < 8; ++j) {
        double l = Lr[lane * 8 + j];
        v[j] = 1.0 / (1.0 + exp(-l));
    }
    double w[8];
    #pragma unroll
    for (int j = 0; j < 8; ++j) w[j] = v[j];

    double kth = -1.0e300;
    for (int it = 0; it < k; ++it) {
        double mv = w[0]; int mj = 0;
        #pragma unroll
        for (int j = 1; j < 8; ++j)
            if (w[j] > mv) { mv = w[j]; mj = j; }
        int mi = lane * 8 + mj;
        #pragma unroll
        for (int off = 32; off; off >>= 1) {
            double ov = __shfl_xor(mv, off);
            int    oi = __shfl_xor(mi, off);
            if (ov > mv || (ov == mv && oi < mi)) { mv = ov; mi = oi; }
        }
        kth = mv;
        if ((mi >> 3) == lane) w[mi & 7] = -1.0e300;
    }

    float o[8];
    #pragma unroll
    for (int j = 0; j < 8; ++j)
        o[j] = (v[j] >= kth && v[j] > 0.2) ? 1.0f : 0.0f;
    float* Op = O + row * (size_t)ncols + lane * 8;
    *(float4*)&Op[0] = *(const float4*)&o[0];
    *(float4*)&Op[4] = *(const float4*)&o[4];
}

extern "C" void kernel_launch(void* const* d_in, const int* in_sizes, int n_in,
                              void* d_out, int out_size, void* d_ws, size_t ws_size,
                              hipStream_t stream) {
    const float* inp = (const float*)d_in[0];
    const float* W1  = (const float*)d_in[1];
    const float* b1  = (const float*)d_in[2];
    const float* W2  = (const float*)d_in[3];
    const float* b2  = (const float*)d_in[4];
    const int*   kp  = (const int*)d_in[5];

    const int H = in_sizes[2];              // 2048
    const int F = in_sizes[4];              // 512
    const int D = in_sizes[1] / H;          // 4096
    const int B = in_sizes[0] / D;          // 16384
    float* out = (float*)d_out;

    const int MAXR = B / 2;                          // 8192
    const size_t szHsplit = (size_t)B * H * 2 * 2;   // h_hi + h_lo = 2^27 B
    const size_t szL32    = (size_t)B * F * 4;       // 32 MiB
    const size_t needMain = szHsplit + szL32 + (size_t)MAXR * 4 + 256;

    if (ws_size >= needMain) {
        ushort* h_hi  = (ushort*)d_ws;
        ushort* h_lo  = h_hi + (size_t)B * H;
        float*  l32   = (float*)((char*)d_ws + szHsplit);
        int*    risky = (int*)((char*)d_ws + szHsplit + szL32);
        int*    cnt   = risky + MAXR;
        double* h64   = (double*)d_ws;                      // alias h_hi/h_lo
        double* L64   = (double*)((char*)d_ws + szHsplit);  // alias l32

        init_repair<<<(MAXR + 255) / 256, 256, 0, stream>>>(risky, cnt, MAXR);
        // fast pass: bf16-split MFMA
        bgemm_split<0, 0><<<dim3(B / BM, H / BN), 256, 0, stream>>>(
            inp, nullptr, nullptr, D, W1, D, b1, h_hi, h_lo, nullptr, H, D);
        bgemm_split<1, 1><<<dim3(B / BM, F / BN), 256, 0, stream>>>(
            nullptr, h_hi, h_lo, H, W2, H, b2, nullptr, nullptr, l32, F, H);
        margin_topk32<<<B / 4, 256, 0, stream>>>(l32, out, F, kp, risky, cnt, MAXR);
        // repair flagged rows in fp64, 16-row tiles
        repair16<float, 0><<<dim3(MAXR / 16, H / BN), 256, 0, stream>>>(
            inp, D, W1, D, b1, h64, H, D, risky, cnt, MAXR);
        repair16<double, 1><<<dim3(MAXR / 16, F / BN), 256, 0, stream>>>(
            h64, H, W2, H, b2, L64, F, H, risky, cnt, MAXR);
        topk64_kernel<<<MAXR / 4, 256, 0, stream>>>(L64, out, F, kp, risky, cnt, MAXR);
    } else {
        // Fallback: full-fp64 chunked pipeline (verified r3).
        int Hc = H, Bc = 0;
        for (;;) {
            size_t perRow = (size_t)F * 8 + (size_t)Hc * 8;
            Bc = (int)((ws_size / perRow) / BM) * BM;
            if (Bc >= BM || Hc <= BM) break;
            Hc >>= 1;
        }
        if (Bc < BM) Bc = BM;
        if (Bc > B)  Bc = B;
        double* L   = (double*)d_ws;
        double* h64 = L + (size_t)Bc * F;

        for (int b0 = 0; b0 < B; b0 += Bc) {
            int bc = (B - b0 < Bc) ? (B - b0) : Bc;
            for (int h0 = 0; h0 < H; h0 += Hc) {
                int hc = (H - h0 < Hc) ? (H - h0) : Hc;
                gemm64<float, 0><<<dim3(bc / BM, hc / BN), 256, 0, stream>>>(
                    inp + (size_t)b0 * D, D, W1 + (size_t)h0 * D, D, b1 + h0,
                    h64, hc, D);
                if (h0 == 0)
                    gemm64<double, 1><<<dim3(bc / BM, F / BN), 256, 0, stream>>>(
                        h64, hc, W2 + h0, H, b2, L, F, hc);
                else
                    gemm64<double, 2><<<dim3(bc / BM, F / BN), 256, 0, stream>>>(
                        h64, hc, W2 + h0, H, b2, L, F, hc);
            }
            topk64_kernel<<<bc / 4, 256, 0, stream>>>(
                L, out + (size_t)b0 * F, F, kp, nullptr, nullptr, 0);
        }
    }
}

// Round 8
// 1625.123 us; speedup vs baseline: 4.7169x; 1.9045x over previous
//
#include <hip/hip_runtime.h>
#include <math.h>
#include <type_traits>

// Fused MLP head with BINARY output (per-row top-k gate + 0.2 hardlim).
// Verified architecture: bf16-split MFMA fast pass (r5) -> logit-margin flags
// (TAU=1e-4, r6) -> fp64 recompute of flagged rows only (r3-verified numerics).
// r7: repair kernels restructured from staged-tile GEMM (latency-serial: 1.5ms
// at 1.5% VALUBusy) to streaming row-gather matvecs: x staged once in LDS,
// per-thread independent W streams, fp64 register accumulators, no per-K
// barriers. ~10x more latency tolerance at the same FLOP count.

#define BM 128
#define BN 128
#define BK 16      // fp64 fallback K-step
#define BKF 32     // bf16 path K-step

#define TAU   1.0e-4f
#define L02F -1.3862943611198906f   /* ln(0.2/0.8) */

typedef __attribute__((ext_vector_type(8))) short bf16x8;
typedef __attribute__((ext_vector_type(4))) float f32x4;

__device__ inline ushort bfhi(float f)   { return (ushort)(__float_as_uint(f) >> 16); }
__device__ inline float  bfhif(float f)  { return __uint_as_float(__float_as_uint(f) & 0xFFFF0000u); }

// ---------------- bf16-split MFMA GEMM (fast pass, r5-verified) ------------
template<int A_PRESPLIT, int OUT_MODE>
__global__ __launch_bounds__(256) void bgemm_split(
    const float*  __restrict__ A32,
    const ushort* __restrict__ Ahg, const ushort* __restrict__ Alg, int lda,
    const float*  __restrict__ W,   int ldw,
    const float*  __restrict__ bias,
    ushort* __restrict__ Chi, ushort* __restrict__ Clo,
    float*  __restrict__ C32, int N, int K)
{
    __shared__ __align__(16) ushort Ah[BM * BKF];
    __shared__ __align__(16) ushort Al[BM * BKF];
    __shared__ __align__(16) ushort Bh[BN * BKF];
    __shared__ __align__(16) ushort Bl[BN * BKF];

    const int t    = threadIdx.x;
    const int lane = t & 63;
    const int wave = t >> 6;
    const int wr   = wave >> 1;
    const int wc   = wave & 1;
    const int l15  = lane & 15;
    const int l4   = lane >> 4;
    const size_t bm = blockIdx.x;
    const size_t bn = blockIdx.y;

    f32x4 acc[4][4];
    #pragma unroll
    for (int mi = 0; mi < 4; ++mi)
        #pragma unroll
        for (int ni = 0; ni < 4; ++ni)
            acc[mi][ni] = (f32x4){0.f, 0.f, 0.f, 0.f};

    for (int k0 = 0; k0 < K; k0 += BKF) {
        if (A_PRESPLIT) {
            #pragma unroll
            for (int i = 0; i < 2; ++i) {
                int c = t + i * 256;
                int row = c >> 2, q = c & 3;
                size_t g = (bm * BM + row) * (size_t)lda + k0 + q * 8;
                *(uint4*)&Ah[row * BKF + q * 8] = *(const uint4*)(Ahg + g);
                *(uint4*)&Al[row * BKF + q * 8] = *(const uint4*)(Alg + g);
            }
        } else {
            #pragma unroll
            for (int i = 0; i < 4; ++i) {
                int c = t + i * 256;
                int row = c >> 3, q = c & 7;
                float4 v = *(const float4*)(A32 + (bm * BM + row) * (size_t)lda + k0 + q * 4);
                ushort4 h, l;
                h.x = bfhi(v.x); l.x = bfhi(v.x - bfhif(v.x));
                h.y = bfhi(v.y); l.y = bfhi(v.y - bfhif(v.y));
                h.z = bfhi(v.z); l.z = bfhi(v.z - bfhif(v.z));
                h.w = bfhi(v.w); l.w = bfhi(v.w - bfhif(v.w));
                *(ushort4*)&Ah[row * BKF + q * 4] = h;
                *(ushort4*)&Al[row * BKF + q * 4] = l;
            }
        }
        #pragma unroll
        for (int i = 0; i < 4; ++i) {
            int c = t + i * 256;
            int row = c >> 3, q = c & 7;
            float4 v = *(const float4*)(W + (bn * BN + row) * (size_t)ldw + k0 + q * 4);
            ushort4 h, l;
            h.x = bfhi(v.x); l.x = bfhi(v.x - bfhif(v.x));
            h.y = bfhi(v.y); l.y = bfhi(v.y - bfhif(v.y));
            h.z = bfhi(v.z); l.z = bfhi(v.z - bfhif(v.z));
            h.w = bfhi(v.w); l.w = bfhi(v.w - bfhif(v.w));
            *(ushort4*)&Bh[row * BKF + q * 4] = h;
            *(ushort4*)&Bl[row * BKF + q * 4] = l;
        }
        __syncthreads();

        bf16x8 ah[4], al[4], bh[4], bl[4];
        #pragma unroll
        for (int mi = 0; mi < 4; ++mi) {
            int r = wr * 64 + mi * 16 + l15;
            ah[mi] = *(const bf16x8*)&Ah[r * BKF + l4 * 8];
            al[mi] = *(const bf16x8*)&Al[r * BKF + l4 * 8];
        }
        #pragma unroll
        for (int ni = 0; ni < 4; ++ni) {
            int r = wc * 64 + ni * 16 + l15;
            bh[ni] = *(const bf16x8*)&Bh[r * BKF + l4 * 8];
            bl[ni] = *(const bf16x8*)&Bl[r * BKF + l4 * 8];
        }
        #pragma unroll
        for (int mi = 0; mi < 4; ++mi)
            #pragma unroll
            for (int ni = 0; ni < 4; ++ni) {
                acc[mi][ni] = __builtin_amdgcn_mfma_f32_16x16x32_bf16(ah[mi], bh[ni], acc[mi][ni], 0, 0, 0);
                acc[mi][ni] = __builtin_amdgcn_mfma_f32_16x16x32_bf16(ah[mi], bl[ni], acc[mi][ni], 0, 0, 0);
                acc[mi][ni] = __builtin_amdgcn_mfma_f32_16x16x32_bf16(al[mi], bh[ni], acc[mi][ni], 0, 0, 0);
                acc[mi][ni] = __builtin_amdgcn_mfma_f32_16x16x32_bf16(al[mi], bl[ni], acc[mi][ni], 0, 0, 0);
            }
        __syncthreads();
    }

    #pragma unroll
    for (int ni = 0; ni < 4; ++ni) {
        int col = (int)bn * BN + wc * 64 + ni * 16 + l15;
        float bv = bias[col];
        #pragma unroll
        for (int mi = 0; mi < 4; ++mi) {
            int rowb = (int)bm * BM + wr * 64 + mi * 16 + l4 * 4;
            #pragma unroll
            for (int r = 0; r < 4; ++r) {
                float v = acc[mi][ni][r] + bv;
                size_t idx = (size_t)(rowb + r) * N + col;
                if (OUT_MODE == 0) {
                    v = fmaxf(v, 0.0f);
                    Chi[idx] = bfhi(v);
                    Clo[idx] = bfhi(v - bfhif(v));
                } else {
                    C32[idx] = v;
                }
            }
        }
    }
}

// ---------------- streaming fp64 repair, stage 1 ---------------------------
// 4 gathered rows x 512 h-cols per block. x rows staged once in LDS (fp32);
// each thread owns 2 cols x 4 rows, streams its 2 W1 rows with independent
// float4 loads, fp64 FMA into registers. No per-K barriers -> latency-tolerant.
__global__ __launch_bounds__(256) void repair_r1(
    const float* __restrict__ inp,
    const float* __restrict__ W1, const float* __restrict__ b1,
    double* __restrict__ h64,
    const int* __restrict__ risky, const int* __restrict__ cnt, int maxr)
{
    int c = *cnt; if (c > maxr) c = maxr;
    const int by = blockIdx.y;
    if (by * 4 >= c) return;
    __shared__ float Xs[4][4096];
    const int t = threadIdx.x;

    int ridx[4];
    #pragma unroll
    for (int r = 0; r < 4; ++r) {
        int slot = by * 4 + r;
        ridx[r] = risky[slot < c ? slot : (c - 1)];
    }
    #pragma unroll
    for (int i = 0; i < 16; ++i) {
        int lin = t + i * 256;             // 0..4095 float4 slots
        int r = lin >> 10, q = lin & 1023;
        *(float4*)&Xs[r][q * 4] = *(const float4*)(inp + (size_t)ridx[r] * 4096 + q * 4);
    }
    __syncthreads();

    const int n0 = blockIdx.x * 512 + t;
    const int n1 = n0 + 256;
    const float* w0 = W1 + (size_t)n0 * 4096;
    const float* w1 = W1 + (size_t)n1 * 4096;
    double acc[2][4] = {};

    for (int k = 0; k < 4096; k += 4) {
        float4 a0 = *(const float4*)(w0 + k);
        float4 a1 = *(const float4*)(w1 + k);
        float xr[4][4];
        #pragma unroll
        for (int r = 0; r < 4; ++r)
            *(float4*)&xr[r][0] = *(const float4*)&Xs[r][k];   // uniform: broadcast
        const float* ap0 = &a0.x;
        const float* ap1 = &a1.x;
        #pragma unroll
        for (int j = 0; j < 4; ++j) {
            double wd0 = (double)ap0[j];
            double wd1 = (double)ap1[j];
            #pragma unroll
            for (int r = 0; r < 4; ++r) {
                double xd = (double)xr[r][j];
                acc[0][r] = fma(wd0, xd, acc[0][r]);
                acc[1][r] = fma(wd1, xd, acc[1][r]);
            }
        }
    }

    double bv0 = (double)b1[n0], bv1 = (double)b1[n1];
    #pragma unroll
    for (int r = 0; r < 4; ++r) {
        int slot = by * 4 + r;
        if (slot < c) {
            h64[(size_t)slot * 2048 + n0] = fmax(acc[0][r] + bv0, 0.0);
            h64[(size_t)slot * 2048 + n1] = fmax(acc[1][r] + bv1, 0.0);
        }
    }
}

// ---------------- streaming fp64 repair, stage 2 ---------------------------
// 4 compact rows x all 512 logit cols per block; h64 rows staged fp64 in LDS.
__global__ __launch_bounds__(256) void repair_r2(
    const double* __restrict__ h64,
    const float* __restrict__ W2, const float* __restrict__ b2,
    double* __restrict__ L64,
    const int* __restrict__ cnt, int maxr)
{
    int c = *cnt; if (c > maxr) c = maxr;
    const int by = blockIdx.y;
    if (by * 4 >= c) return;
    __shared__ double Xs[4][2048];
    const int t = threadIdx.x;

    #pragma unroll
    for (int i = 0; i < 16; ++i) {
        int lin = t + i * 256;             // 0..4095 double2 slots
        int r = lin >> 10, q = lin & 1023;
        int slot = by * 4 + r; if (slot >= c) slot = c - 1;
        *(double2*)&Xs[r][q * 2] = *(const double2*)(h64 + (size_t)slot * 2048 + q * 2);
    }
    __syncthreads();

    const int n0 = t;
    const int n1 = t + 256;
    const float* w0 = W2 + (size_t)n0 * 2048;
    const float* w1 = W2 + (size_t)n1 * 2048;
    double acc[2][4] = {};

    for (int k = 0; k < 2048; k += 4) {
        float4 a0 = *(const float4*)(w0 + k);
        float4 a1 = *(const float4*)(w1 + k);
        double xr[4][4];
        #pragma unroll
        for (int r = 0; r < 4; ++r) {
            *(double2*)&xr[r][0] = *(const double2*)&Xs[r][k];
            *(double2*)&xr[r][2] = *(const double2*)&Xs[r][k + 2];
        }
        const float* ap0 = &a0.x;
        const float* ap1 = &a1.x;
        #pragma unroll
        for (int j = 0; j < 4; ++j) {
            double wd0 = (double)ap0[j];
            double wd1 = (double)ap1[j];
            #pragma unroll
            for (int r = 0; r < 4; ++r) {
                acc[0][r] = fma(wd0, xr[r][j], acc[0][r]);
                acc[1][r] = fma(wd1, xr[r][j], acc[1][r]);
            }
        }
    }

    double bv0 = (double)b2[n0], bv1 = (double)b2[n1];
    #pragma unroll
    for (int r = 0; r < 4; ++r) {
        int slot = by * 4 + r;
        if (slot < c) {
            L64[(size_t)slot * 512 + n0] = acc[0][r] + bv0;
            L64[(size_t)slot * 512 + n1] = acc[1][r] + bv1;
        }
    }
}

// ---------------- fp64 GEMM (r3-verified; fallback tier only) --------------
template<typename TA, int MODE>
__global__ __launch_bounds__(256, 1) void gemm64(
    const TA* __restrict__ A, int lda,
    const float* __restrict__ W, int ldw,
    const float* __restrict__ bias,
    double* __restrict__ out64, int N, int K)
{
    __shared__ double As[BK][BM + 2];
    __shared__ double Bs[BK][BN + 2];
    const int t  = threadIdx.x;
    const int tm = t >> 4;
    const int tn = t & 15;
    const size_t bm = blockIdx.x;
    const size_t bn = blockIdx.y;
    const TA*    Ab = A + bm * BM * (size_t)lda;
    const float* Wb = W + bn * BN * (size_t)ldw;

    double acc[8][8] = {};

    for (int k0 = 0; k0 < K; k0 += BK) {
        #pragma unroll
        for (int i = 0; i < 2; ++i) {
            int f   = t + i * 256;
            int row = f >> 2;
            int kc  = (f & 3) << 2;
            if constexpr (std::is_same<TA, double>::value) {
                double2 v0 = *(const double2*)(Ab + (size_t)row * lda + k0 + kc);
                double2 v1 = *(const double2*)(Ab + (size_t)row * lda + k0 + kc + 2);
                As[kc + 0][row] = v0.x; As[kc + 1][row] = v0.y;
                As[kc + 2][row] = v1.x; As[kc + 3][row] = v1.y;
            } else {
                float4 va = *(const float4*)(Ab + (size_t)row * lda + k0 + kc);
                As[kc + 0][row] = (double)va.x; As[kc + 1][row] = (double)va.y;
                As[kc + 2][row] = (double)va.z; As[kc + 3][row] = (double)va.w;
            }
            float4 vb = *(const float4*)(Wb + (size_t)row * ldw + k0 + kc);
            Bs[kc + 0][row] = (double)vb.x; Bs[kc + 1][row] = (double)vb.y;
            Bs[kc + 2][row] = (double)vb.z; Bs[kc + 3][row] = (double)vb.w;
        }
        __syncthreads();
        #pragma unroll
        for (int k = 0; k < BK; ++k) {
            double a[8], b[8];
            #pragma unroll
            for (int i = 0; i < 4; ++i) {
                *(double2*)&a[i * 2] = *(const double2*)&As[k][tm * 8 + i * 2];
                *(double2*)&b[i * 2] = *(const double2*)&Bs[k][tn * 8 + i * 2];
            }
            #pragma unroll
            for (int i = 0; i < 8; ++i)
                #pragma unroll
                for (int j = 0; j < 8; ++j)
                    acc[i][j] = fma(a[i], b[j], acc[i][j]);
        }
        __syncthreads();
    }

    double bv[8];
    if (MODE != 2) {
        #pragma unroll
        for (int j = 0; j < 8; ++j) bv[j] = (double)bias[bn * BN + tn * 8 + j];
    }

    #pragma unroll
    for (int i = 0; i < 8; ++i) {
        size_t row  = bm * BM + (size_t)tm * 8 + i;
        size_t base = row * (size_t)N + bn * BN + tn * 8;
        #pragma unroll
        for (int j = 0; j < 8; ++j) {
            double v = acc[i][j];
            if (MODE == 0) out64[base + j] = fmax(v + bv[j], 0.0);
            if (MODE == 1) out64[base + j] = v + bv[j];
            if (MODE == 2) out64[base + j] += v;
        }
    }
}

__global__ void init_repair(int* risky, int* cnt, int maxr)
{
    int i = blockIdx.x * 256 + threadIdx.x;
    if (i == 0) *cnt = 0;
    if (i < maxr) risky[i] = 0;
}

// ---------------- fp32 top-k + margin flag + gate (r4-verified) ------------
__global__ __launch_bounds__(256) void margin_topk32(
    const float* __restrict__ L, float* __restrict__ O, int ncols,
    const int* __restrict__ kp, int* __restrict__ risky, int* __restrict__ cnt,
    int maxr)
{
    const int wave = threadIdx.x >> 6;
    const int lane = threadIdx.x & 63;
    const int k = *kp;
    const size_t row = (size_t)blockIdx.x * 4 + wave;
    const float* Lr = L + row * (size_t)ncols;

    float v[8];
    *(float4*)&v[0] = *(const float4*)(Lr + lane * 8);
    *(float4*)&v[4] = *(const float4*)(Lr + lane * 8 + 4);
    float w[8];
    #pragma unroll
    for (int j = 0; j < 8; ++j) w[j] = v[j];

    float kth = -3.0e38f, minD = 3.0e38f;
    for (int it = 0; it < k; ++it) {
        float mv = w[0]; int mj = 0;
        #pragma unroll
        for (int j = 1; j < 8; ++j)
            if (w[j] > mv) { mv = w[j]; mj = j; }
        int mi = lane * 8 + mj;
        #pragma unroll
        for (int off = 32; off; off >>= 1) {
            float ov = __shfl_xor(mv, off);
            int   oi = __shfl_xor(mi, off);
            if (ov > mv || (ov == mv && oi < mi)) { mv = ov; mi = oi; }
        }
        kth = mv;
        minD = fminf(minD, fabsf(mv - L02F));
        if ((mi >> 3) == lane) w[mi & 7] = -3.0e38f;
    }
    float nv = w[0];
    #pragma unroll
    for (int j = 1; j < 8; ++j) nv = fmaxf(nv, w[j]);
    #pragma unroll
    for (int off = 32; off; off >>= 1) nv = fmaxf(nv, __shfl_xor(nv, off));

    bool risk = ((kth - nv) < 2.0f * TAU) || (minD < TAU);
    if (risk && lane == 0) {
        int p = atomicAdd(cnt, 1);
        if (p < maxr) risky[p] = (int)row;
    }

    float o[8];
    #pragma unroll
    for (int j = 0; j < 8; ++j)
        o[j] = (v[j] >= kth && v[j] > L02F) ? 1.0f : 0.0f;
    float* Op = O + row * (size_t)ncols + lane * 8;
    *(float4*)&Op[0] = *(const float4*)&o[0];
    *(float4*)&Op[4] = *(const float4*)&o[4];
}

// ---------------- fp64 top-k (r3-verified), direct or gathered -------------
__global__ __launch_bounds__(256) void topk64_kernel(
    const double* __restrict__ L, float* __restrict__ O, int ncols,
    const int* __restrict__ kp,
    const int* __restrict__ risky, const int* __restrict__ cnt, int maxr)
{
    const int wave = threadIdx.x >> 6;
    const int lane = threadIdx.x & 63;
    const int k = *kp;
    size_t pos = (size_t)blockIdx.x * 4 + wave;
    size_t row = pos;
    if (cnt) {
        int c = *cnt; if (c > maxr) c = maxr;
        if ((int)pos >= c) return;
        row = (size_t)risky[pos];
    }
    const double* Lr = L + pos * (size_t)ncols;

    double v[8];
    #pragma unroll
    for (int j = 0; j < 8; ++j) {
        double l = Lr[lane * 8 + j];
        v[j] = 1.0 / (1.0 + exp(-l));
    }
    double w[8];
    #pragma unroll
    for (int j = 0; j < 8; ++j) w[j] = v[j];

    double kth = -1.0e300;
    for (int it = 0; it < k; ++it) {
        double mv = w[0]; int mj = 0;
        #pragma unroll
        for (int j = 1; j < 8; ++j)
            if (w[j] > mv) { mv = w[j]; mj = j; }
        int mi = lane * 8 + mj;
        #pragma unroll
        for (int off = 32; off; off >>= 1) {
            double ov = __shfl_xor(mv, off);
            int    oi = __shfl_xor(mi, off);
            if (ov > mv || (ov == mv && oi < mi)) { mv = ov; mi = oi; }
        }
        kth = mv;
        if ((mi >> 3) == lane) w[mi & 7] = -1.0e300;
    }

    float o[8];
    #pragma unroll
    for (int j = 0; j < 8; ++j)
        o[j] = (v[j] >= kth && v[j] > 0.2) ? 1.0f : 0.0f;
    float* Op = O + row * (size_t)ncols + lane * 8;
    *(float4*)&Op[0] = *(const float4*)&o[0];
    *(float4*)&Op[4] = *(const float4*)&o[4];
}

extern "C" void kernel_launch(void* const* d_in, const int* in_sizes, int n_in,
                              void* d_out, int out_size, void* d_ws, size_t ws_size,
                              hipStream_t stream) {
    const float* inp = (const float*)d_in[0];
    const float* W1  = (const float*)d_in[1];
    const float* b1  = (const float*)d_in[2];
    const float* W2  = (const float*)d_in[3];
    const float* b2  = (const float*)d_in[4];
    const int*   kp  = (const int*)d_in[5];

    const int H = in_sizes[2];              // 2048
    const int F = in_sizes[4];              // 512
    const int D = in_sizes[1] / H;          // 4096
    const int B = in_sizes[0] / D;          // 16384
    float* out = (float*)d_out;

    const int MAXR = B / 2;                          // 8192
    const size_t szHsplit = (size_t)B * H * 2 * 2;   // h_hi + h_lo = 2^27 B
    const size_t szL32    = (size_t)B * F * 4;       // 32 MiB
    const size_t needMain = szHsplit + szL32 + (size_t)MAXR * 4 + 256;
    const bool   shapeOK  = (D == 4096 && H == 2048 && F == 512);

    if (shapeOK && ws_size >= needMain) {
        ushort* h_hi  = (ushort*)d_ws;
        ushort* h_lo  = h_hi + (size_t)B * H;
        float*  l32   = (float*)((char*)d_ws + szHsplit);
        int*    risky = (int*)((char*)d_ws + szHsplit + szL32);
        int*    cnt   = risky + MAXR;
        double* h64   = (double*)d_ws;                      // alias h_hi/h_lo (consumed)
        double* L64   = (double*)((char*)d_ws + szHsplit);  // alias l32 (consumed)

        init_repair<<<(MAXR + 255) / 256, 256, 0, stream>>>(risky, cnt, MAXR);
        // fast pass: bf16-split MFMA
        bgemm_split<0, 0><<<dim3(B / BM, H / BN), 256, 0, stream>>>(
            inp, nullptr, nullptr, D, W1, D, b1, h_hi, h_lo, nullptr, H, D);
        bgemm_split<1, 1><<<dim3(B / BM, F / BN), 256, 0, stream>>>(
            nullptr, h_hi, h_lo, H, W2, H, b2, nullptr, nullptr, l32, F, H);
        margin_topk32<<<B / 4, 256, 0, stream>>>(l32, out, F, kp, risky, cnt, MAXR);
        // repair flagged rows in fp64: streaming row-gather matvecs
        repair_r1<<<dim3(4, MAXR / 4), 256, 0, stream>>>(
            inp, W1, b1, h64, risky, cnt, MAXR);
        repair_r2<<<dim3(1, MAXR / 4), 256, 0, stream>>>(
            h64, W2, b2, L64, cnt, MAXR);
        topk64_kernel<<<MAXR / 4, 256, 0, stream>>>(L64, out, F, kp, risky, cnt, MAXR);
    } else {
        // Fallback: full-fp64 chunked pipeline (verified r3).
        int Hc = H, Bc = 0;
        for (;;) {
            size_t perRow = (size_t)F * 8 + (size_t)Hc * 8;
            Bc = (int)((ws_size / perRow) / BM) * BM;
            if (Bc >= BM || Hc <= BM) break;
            Hc >>= 1;
        }
        if (Bc < BM) Bc = BM;
        if (Bc > B)  Bc = B;
        double* L   = (double*)d_ws;
        double* h64 = L + (size_t)Bc * F;

        for (int b0 = 0; b0 < B; b0 += Bc) {
            int bc = (B - b0 < Bc) ? (B - b0) : Bc;
            for (int h0 = 0; h0 < H; h0 += Hc) {
                int hc = (H - h0 < Hc) ? (H - h0) : Hc;
                gemm64<float, 0><<<dim3(bc / BM, hc / BN), 256, 0, stream>>>(
                    inp + (size_t)b0 * D, D, W1 + (size_t)h0 * D, D, b1 + h0,
                    h64, hc, D);
                if (h0 == 0)
                    gemm64<double, 1><<<dim3(bc / BM, F / BN), 256, 0, stream>>>(
                        h64, hc, W2 + h0, H, b2, L, F, hc);
                else
                    gemm64<double, 2><<<dim3(bc / BM, F / BN), 256, 0, stream>>>(
                        h64, hc, W2 + h0, H, b2, L, F, hc);
            }
            topk64_kernel<<<bc / 4, 256, 0, stream>>>(
                L, out + (size_t)b0 * F, F, kp, nullptr, nullptr, 0);
        }
    }
}

// Round 9
// 1500.370 us; speedup vs baseline: 5.1091x; 1.0831x over previous
//
#include <hip/hip_runtime.h>
#include <math.h>
#include <type_traits>

// Fused MLP head with BINARY output (per-row top-k gate + 0.2 hardlim).
// Verified architecture: bf16-split MFMA fast pass (r5) -> logit-margin flags
// (TAU=1e-4, r6) -> streaming fp64 repair of flagged rows (r7).
// r8: (a) drop lo*lo MFMA product (4->3; residual ~2.5e-6 RMS << TAU net),
//     (b) pre-split W1/W2 into global hi/lo bf16 once (kills the 128x
//         redundant in-GEMM weight conversion; +37.5 MiB ws, tiered).

#define BM 128
#define BN 128
#define BK 16      // fp64 fallback K-step
#define BKF 32     // bf16 path K-step

#define TAU   1.0e-4f
#define L02F -1.3862943611198906f   /* ln(0.2/0.8) */

typedef __attribute__((ext_vector_type(8))) short bf16x8;
typedef __attribute__((ext_vector_type(4))) float f32x4;

__device__ inline ushort bfhi(float f)   { return (ushort)(__float_as_uint(f) >> 16); }
__device__ inline float  bfhif(float f)  { return __uint_as_float(__float_as_uint(f) & 0xFFFF0000u); }

// ---------------- fp32 -> (hi, lo) bf16 split, elementwise -----------------
__global__ __launch_bounds__(256) void split_kernel(
    const float* __restrict__ src, ushort* __restrict__ hi,
    ushort* __restrict__ lo, size_t n4)
{
    size_t i = (size_t)blockIdx.x * 256 + threadIdx.x;
    size_t stride = (size_t)gridDim.x * 256;
    for (; i < n4; i += stride) {
        float4 v = ((const float4*)src)[i];
        ushort4 h, l;
        h.x = bfhi(v.x); l.x = bfhi(v.x - bfhif(v.x));
        h.y = bfhi(v.y); l.y = bfhi(v.y - bfhif(v.y));
        h.z = bfhi(v.z); l.z = bfhi(v.z - bfhif(v.z));
        h.w = bfhi(v.w); l.w = bfhi(v.w - bfhif(v.w));
        ((ushort4*)hi)[i] = h;
        ((ushort4*)lo)[i] = l;
    }
}

// ---------------- bf16-split MFMA GEMM (fast pass) -------------------------
// 3-product split: ah*bh + ah*bl + al*bh (ll dropped, ~2.5e-6 RMS residual).
// A_PRESPLIT / W_PRESPLIT: operand comes as hi/lo ushort arrays (pure copies)
// vs fp32 (convert while staging). OUT_MODE 0: relu -> split pair; 1: fp32.
template<int A_PRESPLIT, int W_PRESPLIT, int OUT_MODE>
__global__ __launch_bounds__(256) void bgemm_split(
    const float*  __restrict__ A32,
    const ushort* __restrict__ Ahg, const ushort* __restrict__ Alg, int lda,
    const float*  __restrict__ W32,
    const ushort* __restrict__ Whg, const ushort* __restrict__ Wlg, int ldw,
    const float*  __restrict__ bias,
    ushort* __restrict__ Chi, ushort* __restrict__ Clo,
    float*  __restrict__ C32, int N, int K)
{
    __shared__ __align__(16) ushort Ah[BM * BKF];
    __shared__ __align__(16) ushort Al[BM * BKF];
    __shared__ __align__(16) ushort Bh[BN * BKF];
    __shared__ __align__(16) ushort Bl[BN * BKF];

    const int t    = threadIdx.x;
    const int lane = t & 63;
    const int wave = t >> 6;
    const int wr   = wave >> 1;
    const int wc   = wave & 1;
    const int l15  = lane & 15;
    const int l4   = lane >> 4;
    const size_t bm = blockIdx.x;
    const size_t bn = blockIdx.y;

    f32x4 acc[4][4];
    #pragma unroll
    for (int mi = 0; mi < 4; ++mi)
        #pragma unroll
        for (int ni = 0; ni < 4; ++ni)
            acc[mi][ni] = (f32x4){0.f, 0.f, 0.f, 0.f};

    for (int k0 = 0; k0 < K; k0 += BKF) {
        if (A_PRESPLIT) {
            #pragma unroll
            for (int i = 0; i < 2; ++i) {
                int c = t + i * 256;
                int row = c >> 2, q = c & 3;
                size_t g = (bm * BM + row) * (size_t)lda + k0 + q * 8;
                *(uint4*)&Ah[row * BKF + q * 8] = *(const uint4*)(Ahg + g);
                *(uint4*)&Al[row * BKF + q * 8] = *(const uint4*)(Alg + g);
            }
        } else {
            #pragma unroll
            for (int i = 0; i < 4; ++i) {
                int c = t + i * 256;
                int row = c >> 3, q = c & 7;
                float4 v = *(const float4*)(A32 + (bm * BM + row) * (size_t)lda + k0 + q * 4);
                ushort4 h, l;
                h.x = bfhi(v.x); l.x = bfhi(v.x - bfhif(v.x));
                h.y = bfhi(v.y); l.y = bfhi(v.y - bfhif(v.y));
                h.z = bfhi(v.z); l.z = bfhi(v.z - bfhif(v.z));
                h.w = bfhi(v.w); l.w = bfhi(v.w - bfhif(v.w));
                *(ushort4*)&Ah[row * BKF + q * 4] = h;
                *(ushort4*)&Al[row * BKF + q * 4] = l;
            }
        }
        if (W_PRESPLIT) {
            #pragma unroll
            for (int i = 0; i < 2; ++i) {
                int c = t + i * 256;
                int row = c >> 2, q = c & 3;
                size_t g = (bn * BN + row) * (size_t)ldw + k0 + q * 8;
                *(uint4*)&Bh[row * BKF + q * 8] = *(const uint4*)(Whg + g);
                *(uint4*)&Bl[row * BKF + q * 8] = *(const uint4*)(Wlg + g);
            }
        } else {
            #pragma unroll
            for (int i = 0; i < 4; ++i) {
                int c = t + i * 256;
                int row = c >> 3, q = c & 7;
                float4 v = *(const float4*)(W32 + (bn * BN + row) * (size_t)ldw + k0 + q * 4);
                ushort4 h, l;
                h.x = bfhi(v.x); l.x = bfhi(v.x - bfhif(v.x));
                h.y = bfhi(v.y); l.y = bfhi(v.y - bfhif(v.y));
                h.z = bfhi(v.z); l.z = bfhi(v.z - bfhif(v.z));
                h.w = bfhi(v.w); l.w = bfhi(v.w - bfhif(v.w));
                *(ushort4*)&Bh[row * BKF + q * 4] = h;
                *(ushort4*)&Bl[row * BKF + q * 4] = l;
            }
        }
        __syncthreads();

        bf16x8 ah[4], al[4], bh[4], bl[4];
        #pragma unroll
        for (int mi = 0; mi < 4; ++mi) {
            int r = wr * 64 + mi * 16 + l15;
            ah[mi] = *(const bf16x8*)&Ah[r * BKF + l4 * 8];
            al[mi] = *(const bf16x8*)&Al[r * BKF + l4 * 8];
        }
        #pragma unroll
        for (int ni = 0; ni < 4; ++ni) {
            int r = wc * 64 + ni * 16 + l15;
            bh[ni] = *(const bf16x8*)&Bh[r * BKF + l4 * 8];
            bl[ni] = *(const bf16x8*)&Bl[r * BKF + l4 * 8];
        }
        #pragma unroll
        for (int mi = 0; mi < 4; ++mi)
            #pragma unroll
            for (int ni = 0; ni < 4; ++ni) {
                acc[mi][ni] = __builtin_amdgcn_mfma_f32_16x16x32_bf16(ah[mi], bh[ni], acc[mi][ni], 0, 0, 0);
                acc[mi][ni] = __builtin_amdgcn_mfma_f32_16x16x32_bf16(ah[mi], bl[ni], acc[mi][ni], 0, 0, 0);
                acc[mi][ni] = __builtin_amdgcn_mfma_f32_16x16x32_bf16(al[mi], bh[ni], acc[mi][ni], 0, 0, 0);
            }
        __syncthreads();
    }

    #pragma unroll
    for (int ni = 0; ni < 4; ++ni) {
        int col = (int)bn * BN + wc * 64 + ni * 16 + l15;
        float bv = bias[col];
        #pragma unroll
        for (int mi = 0; mi < 4; ++mi) {
            int rowb = (int)bm * BM + wr * 64 + mi * 16 + l4 * 4;
            #pragma unroll
            for (int r = 0; r < 4; ++r) {
                float v = acc[mi][ni][r] + bv;
                size_t idx = (size_t)(rowb + r) * N + col;
                if (OUT_MODE == 0) {
                    v = fmaxf(v, 0.0f);
                    Chi[idx] = bfhi(v);
                    Clo[idx] = bfhi(v - bfhif(v));
                } else {
                    C32[idx] = v;
                }
            }
        }
    }
}

// ---------------- streaming fp64 repair, stage 1 (r7-verified) -------------
__global__ __launch_bounds__(256) void repair_r1(
    const float* __restrict__ inp,
    const float* __restrict__ W1, const float* __restrict__ b1,
    double* __restrict__ h64,
    const int* __restrict__ risky, const int* __restrict__ cnt, int maxr)
{
    int c = *cnt; if (c > maxr) c = maxr;
    const int by = blockIdx.y;
    if (by * 4 >= c) return;
    __shared__ float Xs[4][4096];
    const int t = threadIdx.x;

    int ridx[4];
    #pragma unroll
    for (int r = 0; r < 4; ++r) {
        int slot = by * 4 + r;
        ridx[r] = risky[slot < c ? slot : (c - 1)];
    }
    #pragma unroll
    for (int i = 0; i < 16; ++i) {
        int lin = t + i * 256;
        int r = lin >> 10, q = lin & 1023;
        *(float4*)&Xs[r][q * 4] = *(const float4*)(inp + (size_t)ridx[r] * 4096 + q * 4);
    }
    __syncthreads();

    const int n0 = blockIdx.x * 512 + t;
    const int n1 = n0 + 256;
    const float* w0 = W1 + (size_t)n0 * 4096;
    const float* w1 = W1 + (size_t)n1 * 4096;
    double acc[2][4] = {};

    for (int k = 0; k < 4096; k += 4) {
        float4 a0 = *(const float4*)(w0 + k);
        float4 a1 = *(const float4*)(w1 + k);
        float xr[4][4];
        #pragma unroll
        for (int r = 0; r < 4; ++r)
            *(float4*)&xr[r][0] = *(const float4*)&Xs[r][k];
        const float* ap0 = &a0.x;
        const float* ap1 = &a1.x;
        #pragma unroll
        for (int j = 0; j < 4; ++j) {
            double wd0 = (double)ap0[j];
            double wd1 = (double)ap1[j];
            #pragma unroll
            for (int r = 0; r < 4; ++r) {
                double xd = (double)xr[r][j];
                acc[0][r] = fma(wd0, xd, acc[0][r]);
                acc[1][r] = fma(wd1, xd, acc[1][r]);
            }
        }
    }

    double bv0 = (double)b1[n0], bv1 = (double)b1[n1];
    #pragma unroll
    for (int r = 0; r < 4; ++r) {
        int slot = by * 4 + r;
        if (slot < c) {
            h64[(size_t)slot * 2048 + n0] = fmax(acc[0][r] + bv0, 0.0);
            h64[(size_t)slot * 2048 + n1] = fmax(acc[1][r] + bv1, 0.0);
        }
    }
}

// ---------------- streaming fp64 repair, stage 2 (r7-verified) -------------
__global__ __launch_bounds__(256) void repair_r2(
    const double* __restrict__ h64,
    const float* __restrict__ W2, const float* __restrict__ b2,
    double* __restrict__ L64,
    const int* __restrict__ cnt, int maxr)
{
    int c = *cnt; if (c > maxr) c = maxr;
    const int by = blockIdx.y;
    if (by * 4 >= c) return;
    __shared__ double Xs[4][2048];
    const int t = threadIdx.x;

    #pragma unroll
    for (int i = 0; i < 16; ++i) {
        int lin = t + i * 256;
        int r = lin >> 10, q = lin & 1023;
        int slot = by * 4 + r; if (slot >= c) slot = c - 1;
        *(double2*)&Xs[r][q * 2] = *(const double2*)(h64 + (size_t)slot * 2048 + q * 2);
    }
    __syncthreads();

    const int n0 = t;
    const int n1 = t + 256;
    const float* w0 = W2 + (size_t)n0 * 2048;
    const float* w1 = W2 + (size_t)n1 * 2048;
    double acc[2][4] = {};

    for (int k = 0; k < 2048; k += 4) {
        float4 a0 = *(const float4*)(w0 + k);
        float4 a1 = *(const float4*)(w1 + k);
        double xr[4][4];
        #pragma unroll
        for (int r = 0; r < 4; ++r) {
            *(double2*)&xr[r][0] = *(const double2*)&Xs[r][k];
            *(double2*)&xr[r][2] = *(const double2*)&Xs[r][k + 2];
        }
        const float* ap0 = &a0.x;
        const float* ap1 = &a1.x;
        #pragma unroll
        for (int j = 0; j < 4; ++j) {
            double wd0 = (double)ap0[j];
            double wd1 = (double)ap1[j];
            #pragma unroll
            for (int r = 0; r < 4; ++r) {
                acc[0][r] = fma(wd0, xr[r][j], acc[0][r]);
                acc[1][r] = fma(wd1, xr[r][j], acc[1][r]);
            }
        }
    }

    double bv0 = (double)b2[n0], bv1 = (double)b2[n1];
    #pragma unroll
    for (int r = 0; r < 4; ++r) {
        int slot = by * 4 + r;
        if (slot < c) {
            L64[(size_t)slot * 512 + n0] = acc[0][r] + bv0;
            L64[(size_t)slot * 512 + n1] = acc[1][r] + bv1;
        }
    }
}

// ---------------- fp64 GEMM (r3-verified; fallback tier only) --------------
template<typename TA, int MODE>
__global__ __launch_bounds__(256, 1) void gemm64(
    const TA* __restrict__ A, int lda,
    const float* __restrict__ W, int ldw,
    const float* __restrict__ bias,
    double* __restrict__ out64, int N, int K)
{
    __shared__ double As[BK][BM + 2];
    __shared__ double Bs[BK][BN + 2];
    const int t  = threadIdx.x;
    const int tm = t >> 4;
    const int tn = t & 15;
    const size_t bm = blockIdx.x;
    const size_t bn = blockIdx.y;
    const TA*    Ab = A + bm * BM * (size_t)lda;
    const float* Wb = W + bn * BN * (size_t)ldw;

    double acc[8][8] = {};

    for (int k0 = 0; k0 < K; k0 += BK) {
        #pragma unroll
        for (int i = 0; i < 2; ++i) {
            int f   = t + i * 256;
            int row = f >> 2;
            int kc  = (f & 3) << 2;
            if constexpr (std::is_same<TA, double>::value) {
                double2 v0 = *(const double2*)(Ab + (size_t)row * lda + k0 + kc);
                double2 v1 = *(const double2*)(Ab + (size_t)row * lda + k0 + kc + 2);
                As[kc + 0][row] = v0.x; As[kc + 1][row] = v0.y;
                As[kc + 2][row] = v1.x; As[kc + 3][row] = v1.y;
            } else {
                float4 va = *(const float4*)(Ab + (size_t)row * lda + k0 + kc);
                As[kc + 0][row] = (double)va.x; As[kc + 1][row] = (double)va.y;
                As[kc + 2][row] = (double)va.z; As[kc + 3][row] = (double)va.w;
            }
            float4 vb = *(const float4*)(Wb + (size_t)row * ldw + k0 + kc);
            Bs[kc + 0][row] = (double)vb.x; Bs[kc + 1][row] = (double)vb.y;
            Bs[kc + 2][row] = (double)vb.z; Bs[kc + 3][row] = (double)vb.w;
        }
        __syncthreads();
        #pragma unroll
        for (int k = 0; k < BK; ++k) {
            double a[8], b[8];
            #pragma unroll
            for (int i = 0; i < 4; ++i) {
                *(double2*)&a[i * 2] = *(const double2*)&As[k][tm * 8 + i * 2];
                *(double2*)&b[i * 2] = *(const double2*)&Bs[k][tn * 8 + i * 2];
            }
            #pragma unroll
            for (int i = 0; i < 8; ++i)
                #pragma unroll
                for (int j = 0; j < 8; ++j)
                    acc[i][j] = fma(a[i], b[j], acc[i][j]);
        }
        __syncthreads();
    }

    double bv[8];
    if (MODE != 2) {
        #pragma unroll
        for (int j = 0; j < 8; ++j) bv[j] = (double)bias[bn * BN + tn * 8 + j];
    }

    #pragma unroll
    for (int i = 0; i < 8; ++i) {
        size_t row  = bm * BM + (size_t)tm * 8 + i;
        size_t base = row * (size_t)N + bn * BN + tn * 8;
        #pragma unroll
        for (int j = 0; j < 8; ++j) {
            double v = acc[i][j];
            if (MODE == 0) out64[base + j] = fmax(v + bv[j], 0.0);
            if (MODE == 1) out64[base + j] = v + bv[j];
            if (MODE == 2) out64[base + j] += v;
        }
    }
}

__global__ void init_repair(int* risky, int* cnt, int maxr)
{
    int i = blockIdx.x * 256 + threadIdx.x;
    if (i == 0) *cnt = 0;
    if (i < maxr) risky[i] = 0;
}

// ---------------- fp32 top-k + margin flag + gate (r4-verified) ------------
__global__ __launch_bounds__(256) void margin_topk32(
    const float* __restrict__ L, float* __restrict__ O, int ncols,
    const int* __restrict__ kp, int* __restrict__ risky, int* __restrict__ cnt,
    int maxr)
{
    const int wave = threadIdx.x >> 6;
    const int lane = threadIdx.x & 63;
    const int k = *kp;
    const size_t row = (size_t)blockIdx.x * 4 + wave;
    const float* Lr = L + row * (size_t)ncols;

    float v[8];
    *(float4*)&v[0] = *(const float4*)(Lr + lane * 8);
    *(float4*)&v[4] = *(const float4*)(Lr + lane * 8 + 4);
    float w[8];
    #pragma unroll
    for (int j = 0; j < 8; ++j) w[j] = v[j];

    float kth = -3.0e38f, minD = 3.0e38f;
    for (int it = 0; it < k; ++it) {
        float mv = w[0]; int mj = 0;
        #pragma unroll
        for (int j = 1; j < 8; ++j)
            if (w[j] > mv) { mv = w[j]; mj = j; }
        int mi = lane * 8 + mj;
        #pragma unroll
        for (int off = 32; off; off >>= 1) {
            float ov = __shfl_xor(mv, off);
            int   oi = __shfl_xor(mi, off);
            if (ov > mv || (ov == mv && oi < mi)) { mv = ov; mi = oi; }
        }
        kth = mv;
        minD = fminf(minD, fabsf(mv - L02F));
        if ((mi >> 3) == lane) w[mi & 7] = -3.0e38f;
    }
    float nv = w[0];
    #pragma unroll
    for (int j = 1; j < 8; ++j) nv = fmaxf(nv, w[j]);
    #pragma unroll
    for (int off = 32; off; off >>= 1) nv = fmaxf(nv, __shfl_xor(nv, off));

    bool risk = ((kth - nv) < 2.0f * TAU) || (minD < TAU);
    if (risk && lane == 0) {
        int p = atomicAdd(cnt, 1);
        if (p < maxr) risky[p] = (int)row;
    }

    float o[8];
    #pragma unroll
    for (int j = 0; j < 8; ++j)
        o[j] = (v[j] >= kth && v[j] > L02F) ? 1.0f : 0.0f;
    float* Op = O + row * (size_t)ncols + lane * 8;
    *(float4*)&Op[0] = *(const float4*)&o[0];
    *(float4*)&Op[4] = *(const float4*)&o[4];
}

// ---------------- fp64 top-k (r3-verified), direct or gathered -------------
__global__ __launch_bounds__(256) void topk64_kernel(
    const double* __restrict__ L, float* __restrict__ O, int ncols,
    const int* __restrict__ kp,
    const int* __restrict__ risky, const int* __restrict__ cnt, int maxr)
{
    const int wave = threadIdx.x >> 6;
    const int lane = threadIdx.x & 63;
    const int k = *kp;
    size_t pos = (size_t)blockIdx.x * 4 + wave;
    size_t row = pos;
    if (cnt) {
        int c = *cnt; if (c > maxr) c = maxr;
        if ((int)pos >= c) return;
        row = (size_t)risky[pos];
    }
    const double* Lr = L + pos * (size_t)ncols;

    double v[8];
    #pragma unroll
    for (int j = 0; j < 8; ++j) {
        double l = Lr[lane * 8 + j];
        v[j] = 1.0 / (1.0 + exp(-l));
    }
    double w[8];
    #pragma unroll
    for (int j = 0; j < 8; ++j) w[j] = v[j];

    double kth = -1.0e300;
    for (int it = 0; it < k; ++it) {
        double mv = w[0]; int mj = 0;
        #pragma unroll
        for (int j = 1; j < 8; ++j)
            if (w[j] > mv) { mv = w[j]; mj = j; }
        int mi = lane * 8 + mj;
        #pragma unroll
        for (int off = 32; off; off >>= 1) {
            double ov = __shfl_xor(mv, off);
            int    oi = __shfl_xor(mi, off);
            if (ov > mv || (ov == mv && oi < mi)) { mv = ov; mi = oi; }
        }
        kth = mv;
        if ((mi >> 3) == lane) w[mi & 7] = -1.0e300;
    }

    float o[8];
    #pragma unroll
    for (int j = 0; j < 8; ++j)
        o[j] = (v[j] >= kth && v[j] > 0.2) ? 1.0f : 0.0f;
    float* Op = O + row * (size_t)ncols + lane * 8;
    *(float4*)&Op[0] = *(const float4*)&o[0];
    *(float4*)&Op[4] = *(const float4*)&o[4];
}

extern "C" void kernel_launch(void* const* d_in, const int* in_sizes, int n_in,
                              void* d_out, int out_size, void* d_ws, size_t ws_size,
                              hipStream_t stream) {
    const float* inp = (const float*)d_in[0];
    const float* W1  = (const float*)d_in[1];
    const float* b1  = (const float*)d_in[2];
    const float* W2  = (const float*)d_in[3];
    const float* b2  = (const float*)d_in[4];
    const int*   kp  = (const int*)d_in[5];

    const int H = in_sizes[2];              // 2048
    const int F = in_sizes[4];              // 512
    const int D = in_sizes[1] / H;          // 4096
    const int B = in_sizes[0] / D;          // 16384
    float* out = (float*)d_out;

    const int MAXR = B / 2;                          // 8192
    const size_t szHsplit = (size_t)B * H * 2 * 2;   // h_hi + h_lo = 2^27 B
    const size_t szL32    = (size_t)B * F * 4;       // 32 MiB
    const size_t szRisky  = (size_t)MAXR * 4 + 256;
    const size_t szW1s    = (size_t)H * D * 2;       // one of W1 hi/lo
    const size_t szW2s    = (size_t)F * H * 2;       // one of W2 hi/lo
    const size_t needC    = szHsplit + szL32 + szRisky;
    const size_t needB    = needC + 2 * szW1s + 2 * szW2s;
    const bool   shapeOK  = (D == 4096 && H == 2048 && F == 512);

    if (shapeOK && ws_size >= needC) {
        ushort* h_hi  = (ushort*)d_ws;
        ushort* h_lo  = h_hi + (size_t)B * H;
        float*  l32   = (float*)((char*)d_ws + szHsplit);
        int*    risky = (int*)((char*)d_ws + szHsplit + szL32);
        int*    cnt   = risky + MAXR;
        double* h64   = (double*)d_ws;                      // alias h pair (consumed)
        double* L64   = (double*)((char*)d_ws + szHsplit);  // alias l32 (consumed)

        init_repair<<<(MAXR + 255) / 256, 256, 0, stream>>>(risky, cnt, MAXR);

        if (ws_size >= needB) {
            // Tier B: weights pre-split once (kills 128x redundant conversion).
            ushort* w1h = (ushort*)((char*)d_ws + needC);
            ushort* w1l = w1h + (size_t)H * D;
            ushort* w2h = w1l + (size_t)H * D;
            ushort* w2l = w2h + (size_t)F * H;
            split_kernel<<<2048, 256, 0, stream>>>(W1, w1h, w1l, (size_t)H * D / 4);
            split_kernel<<<512, 256, 0, stream>>>(W2, w2h, w2l, (size_t)F * H / 4);
            bgemm_split<0, 1, 0><<<dim3(B / BM, H / BN), 256, 0, stream>>>(
                inp, nullptr, nullptr, D, nullptr, w1h, w1l, D, b1,
                h_hi, h_lo, nullptr, H, D);
            bgemm_split<1, 1, 1><<<dim3(B / BM, F / BN), 256, 0, stream>>>(
                nullptr, h_hi, h_lo, H, nullptr, w2h, w2l, H, b2,
                nullptr, nullptr, l32, F, H);
        } else {
            // Tier C: r7 structure with 3-product MFMA.
            bgemm_split<0, 0, 0><<<dim3(B / BM, H / BN), 256, 0, stream>>>(
                inp, nullptr, nullptr, D, W1, nullptr, nullptr, D, b1,
                h_hi, h_lo, nullptr, H, D);
            bgemm_split<1, 0, 1><<<dim3(B / BM, F / BN), 256, 0, stream>>>(
                nullptr, h_hi, h_lo, H, W2, nullptr, nullptr, H, b2,
                nullptr, nullptr, l32, F, H);
        }

        margin_topk32<<<B / 4, 256, 0, stream>>>(l32, out, F, kp, risky, cnt, MAXR);
        repair_r1<<<dim3(4, MAXR / 4), 256, 0, stream>>>(
            inp, W1, b1, h64, risky, cnt, MAXR);
        repair_r2<<<dim3(1, MAXR / 4), 256, 0, stream>>>(
            h64, W2, b2, L64, cnt, MAXR);
        topk64_kernel<<<MAXR / 4, 256, 0, stream>>>(L64, out, F, kp, risky, cnt, MAXR);
    } else {
        // Fallback: full-fp64 chunked pipeline (verified r3).
        int Hc = H, Bc = 0;
        for (;;) {
            size_t perRow = (size_t)F * 8 + (size_t)Hc * 8;
            Bc = (int)((ws_size / perRow) / BM) * BM;
            if (Bc >= BM || Hc <= BM) break;
            Hc >>= 1;
        }
        if (Bc < BM) Bc = BM;
        if (Bc > B)  Bc = B;
        double* L   = (double*)d_ws;
        double* h64 = L + (size_t)Bc * F;

        for (int b0 = 0; b0 < B; b0 += Bc) {
            int bc = (B - b0 < Bc) ? (B - b0) : Bc;
            for (int h0 = 0; h0 < H; h0 += Hc) {
                int hc = (H - h0 < Hc) ? (H - h0) : Hc;
                gemm64<float, 0><<<dim3(bc / BM, hc / BN), 256, 0, stream>>>(
                    inp + (size_t)b0 * D, D, W1 + (size_t)h0 * D, D, b1 + h0,
                    h64, hc, D);
                if (h0 == 0)
                    gemm64<double, 1><<<dim3(bc / BM, F / BN), 256, 0, stream>>>(
                        h64, hc, W2 + h0, H, b2, L, F, hc);
                else
                    gemm64<double, 2><<<dim3(bc / BM, F / BN), 256, 0, stream>>>(
                        h64, hc, W2 + h0, H, b2, L, F, hc);
            }
            topk64_kernel<<<bc / 4, 256, 0, stream>>>(
                L, out + (size_t)b0 * F, F, kp, nullptr, nullptr, 0);
        }
    }
}